// Round 14
// baseline (645.773 us; speedup 1.0000x reference)
//
#include <hip/hip_runtime.h>
#include <math.h>

// ---------------------------------------------------------------------------
// Fused transformer block w/ MoE (B=2,T=2048,C=1024,H=16,D=64,E=8,topK=2)
// Round 14: r13 base + fc moved to 256^2/BK=64/8-wave 2-phase dbuf GEMM
// (r6 loop + r7 exact-table, swizzled; grouped-GEMM catalog-validated).
// ---------------------------------------------------------------------------

typedef __bf16 b16v8 __attribute__((ext_vector_type(8)));
typedef float f32x4 __attribute__((ext_vector_type(4)));

#define MFMA(a, b, c) __builtin_amdgcn_mfma_f32_16x16x32_bf16(a, b, c, 0, 0, 0)

#define GLOAD_LDS16(g, l)                                          \
  __builtin_amdgcn_global_load_lds(                                \
      (const __attribute__((address_space(1))) void*)(g),          \
      (__attribute__((address_space(3))) void*)(l), 16, 0, 0)

#define SYNC_VM0()                                       \
  do {                                                   \
    asm volatile("s_waitcnt vmcnt(0)" ::: "memory");     \
    __builtin_amdgcn_s_barrier();                        \
    asm volatile("" ::: "memory");                       \
  } while (0)

constexpr int Bc = 2, Tc = 2048, Cc = 1024, Hc = 16, Dc = 64;
constexpr int Nc = Bc * Tc;       // 4096 tokens
constexpr int HIDc = 4096;        // 4*C
constexpr int Ec = 8;
constexpr int NPAIR = Nc * 2;     // 8192
constexpr int NRBMAX = NPAIR / 128 + Ec;    // 72  (128-stride table)
constexpr int NRB2MAX = NPAIR / 256 + Ec;   // 40  (256-stride table)
constexpr float LOG2E = 1.4426950408889634f;

__device__ inline unsigned short f32_bf16(float f) {
  union { float f; unsigned u; } x; x.f = f;
  unsigned r = x.u + 0x7fffu + ((x.u >> 16) & 1u);   // RNE
  return (unsigned short)(r >> 16);
}

// gelu(x) = x * sigmoid(1.595769122*(x+0.044715x^3)); exp2-domain
__device__ inline float gelu_f(float x) {
  float t = 2.3021188f * x * (1.f + 0.044715f * x * x);
  float e = __builtin_amdgcn_exp2f(-t);
  return x * __builtin_amdgcn_rcpf(1.f + e);
}

// LDS element index for [row][64-elem] rows with 16B-granule XOR swizzle.
__device__ inline int swz(int row, int g) {
  return row * 64 + ((g ^ (row & 7)) * 8);
}

// ---------------------------------------------------------------------------
// Transpose+convert: src f32 [batch][K][N] -> dst bf16 [batch][N][K]
// 64x64 tile, float4 reads, LDS [64][65], ushort4 writes.
// ---------------------------------------------------------------------------
__global__ __launch_bounds__(256) void convT_kernel(
    const float* __restrict__ src, unsigned short* __restrict__ dst,
    int K, int N) {
  const size_t sb = (size_t)blockIdx.z * K * N;
  const int n0 = blockIdx.x * 64, k0 = blockIdx.y * 64;
  __shared__ float t[64][65];
  const int tid = threadIdx.x;
#pragma unroll
  for (int j = 0; j < 4; ++j) {
    int idx = j * 256 + tid;
    int r = idx >> 4;
    int c4 = (idx & 15) << 2;
    float4 v = *(const float4*)&src[sb + (size_t)(k0 + r) * N + n0 + c4];
    t[r][c4] = v.x; t[r][c4 + 1] = v.y; t[r][c4 + 2] = v.z; t[r][c4 + 3] = v.w;
  }
  __syncthreads();
#pragma unroll
  for (int j = 0; j < 4; ++j) {
    int idx = j * 256 + tid;
    int n = idx >> 4;
    int k4 = (idx & 15) << 2;
    ushort4 o;
    o.x = f32_bf16(t[k4][n]);
    o.y = f32_bf16(t[k4 + 1][n]);
    o.z = f32_bf16(t[k4 + 2][n]);
    o.w = f32_bf16(t[k4 + 3][n]);
    *(ushort4*)&dst[sb + (size_t)(n0 + n) * K + k0 + k4] = o;
  }
}

// ---------------------------------------------------------------------------
// LayerNorm (f32 in -> bf16 out).
// ---------------------------------------------------------------------------
__global__ __launch_bounds__(256) void ln1_kernel(
    const float* __restrict__ x, const float* __restrict__ g,
    const float* __restrict__ b, unsigned short* __restrict__ out) {
  const int row = blockIdx.x;
  const int tid = threadIdx.x;
  const float* xr = x + (size_t)row * Cc;
  float v[4]; float s = 0.f, q = 0.f;
#pragma unroll
  for (int j = 0; j < 4; ++j) { v[j] = xr[tid + j * 256]; s += v[j]; q += v[j] * v[j]; }
#pragma unroll
  for (int m = 1; m <= 32; m <<= 1) { s += __shfl_xor(s, m); q += __shfl_xor(q, m); }
  __shared__ float red[2][4];
  const int w = tid >> 6;
  if ((tid & 63) == 0) { red[0][w] = s; red[1][w] = q; }
  __syncthreads();
  s = red[0][0] + red[0][1] + red[0][2] + red[0][3];
  q = red[1][0] + red[1][1] + red[1][2] + red[1][3];
  const float mean = s * (1.f / Cc);
  const float var = q * (1.f / Cc) - mean * mean;
  const float rstd = rsqrtf(var + 1e-5f);
#pragma unroll
  for (int j = 0; j < 4; ++j) {
    int c = tid + j * 256;
    out[(size_t)row * Cc + c] = f32_bf16((v[j] - mean) * rstd * g[c] + b[c]);
  }
}

// ---------------------------------------------------------------------------
// LN2 + router (f32 router math).
// ---------------------------------------------------------------------------
__global__ __launch_bounds__(256) void ln2_router_kernel(
    const float* __restrict__ x, const float* __restrict__ g,
    const float* __restrict__ b, const float* __restrict__ rw,
    unsigned short* __restrict__ out, int* __restrict__ tki, float* __restrict__ tkp) {
  const int row = blockIdx.x;
  const int tid = threadIdx.x;
  const float* xr = x + (size_t)row * Cc;
  float v[4]; float s = 0.f, q = 0.f;
#pragma unroll
  for (int j = 0; j < 4; ++j) { v[j] = xr[tid + j * 256]; s += v[j]; q += v[j] * v[j]; }
#pragma unroll
  for (int m = 1; m <= 32; m <<= 1) { s += __shfl_xor(s, m); q += __shfl_xor(q, m); }
  __shared__ float red[2][4];
  const int w = tid >> 6;
  if ((tid & 63) == 0) { red[0][w] = s; red[1][w] = q; }
  __syncthreads();
  s = red[0][0] + red[0][1] + red[0][2] + red[0][3];
  q = red[1][0] + red[1][1] + red[1][2] + red[1][3];
  const float mean = s * (1.f / Cc);
  const float var = q * (1.f / Cc) - mean * mean;
  const float rstd = rsqrtf(var + 1e-5f);
  float lg[8] = {0.f, 0.f, 0.f, 0.f, 0.f, 0.f, 0.f, 0.f};
#pragma unroll
  for (int j = 0; j < 4; ++j) {
    int c = tid + j * 256;
    float nv = (v[j] - mean) * rstd * g[c] + b[c];
    out[(size_t)row * Cc + c] = f32_bf16(nv);
    const float* rwc = rw + c * 8;
#pragma unroll
    for (int e = 0; e < 8; ++e) lg[e] += nv * rwc[e];
  }
#pragma unroll
  for (int m = 1; m <= 32; m <<= 1) {
#pragma unroll
    for (int e = 0; e < 8; ++e) lg[e] += __shfl_xor(lg[e], m);
  }
  __shared__ float rl[4][8];
  if ((tid & 63) == 0) {
#pragma unroll
    for (int e = 0; e < 8; ++e) rl[w][e] = lg[e];
  }
  __syncthreads();
  if (tid == 0) {
    float L[8];
#pragma unroll
    for (int e = 0; e < 8; ++e) L[e] = rl[0][e] + rl[1][e] + rl[2][e] + rl[3][e];
    int i1 = 0;
    for (int e = 1; e < 8; ++e) if (L[e] > L[i1]) i1 = e;
    int i2 = (i1 == 0) ? 1 : 0;
    for (int e = 0; e < 8; ++e) if (e != i1 && L[e] > L[i2]) i2 = e;
    float e2 = expf(L[i2] - L[i1]);
    float inv = 1.f / (1.f + e2);
    tki[row * 2] = i1; tki[row * 2 + 1] = i2;
    tkp[row * 2] = inv; tkp[row * 2 + 1] = e2 * inv;
  }
}

// ---------------------------------------------------------------------------
// Routing: counts -> offsets + rowblock tables (128- and 256-stride).
// ---------------------------------------------------------------------------
__global__ __launch_bounds__(256) void count_kernel(
    const int* __restrict__ tki, int* __restrict__ counts) {
  int n = blockIdx.x * 256 + threadIdx.x;
  if (n >= Nc) return;
  atomicAdd(&counts[tki[n * 2]], 1);
  atomicAdd(&counts[tki[n * 2 + 1]], 1);
}

__global__ void scan_kernel(const int* __restrict__ counts,
                            int* __restrict__ eoff, int* __restrict__ cursor,
                            int* __restrict__ tbl_e, int* __restrict__ tbl_r0,
                            int* __restrict__ tbl_n,
                            int* __restrict__ tbl2_e, int* __restrict__ tbl2_r0,
                            int* __restrict__ tbl2_n) {
  if (threadIdx.x == 0 && blockIdx.x == 0) {
    int s = 0, nb = 0, nb2 = 0;
    for (int e = 0; e < Ec; ++e) {
      eoff[e] = s; cursor[e] = s;
      for (int r = 0; r < counts[e]; r += 128) {
        tbl_e[nb] = e; tbl_r0[nb] = r; ++nb;
      }
      for (int r = 0; r < counts[e]; r += 256) {
        tbl2_e[nb2] = e; tbl2_r0[nb2] = r; ++nb2;
      }
      s += counts[e];
    }
    eoff[Ec] = s;
    *tbl_n = nb;
    *tbl2_n = nb2;
  }
}

__global__ __launch_bounds__(256) void assign_kernel(
    const int* __restrict__ tki, int* __restrict__ cursor,
    int* __restrict__ slot_tok, int* __restrict__ tok2slot) {
  int n = blockIdx.x * 256 + threadIdx.x;
  if (n >= Nc) return;
#pragma unroll
  for (int kk = 0; kk < 2; ++kk) {
    int e = tki[n * 2 + kk];
    int slot = atomicAdd(&cursor[e], 1);
    slot_tok[slot] = n;
    tok2slot[n * 2 + kk] = slot;
  }
}

// ---------------------------------------------------------------------------
struct GArgs {
  const unsigned short* A;    // bf16 [M][lda]
  const unsigned short* Bt;   // bf16 [N][ldb] (+ e*Bstride)
  const float* bias;          // f32 [N]      (+ e*biasStride)
  int M, N, K, lda, ldb, klen;
  size_t Bstride; int biasStride;
  const int* eoff;            // [E+1] (MoE modes)
  const int* slot_tok;
  const int* tbl_e;           // rowblock table
  const int* tbl_r0;
  const int* tbl_n;
  float* outF;                // MODE 1: out, MODE 3: pairout
  const float* resid;         // MODE 1
  unsigned short* outB;       // MODE 2: he ; MODE 0: q
  unsigned short* outK;       // MODE 0: k
  unsigned short* outV;       // MODE 0: v^T [B,H,D,T]
};

// ---------------------------------------------------------------------------
// 128x128 tile, BK=64, 4 waves, SINGLE buffer (r8 structure, session best at
// 128^2). MODE: 0=QKV scatter, 1=proj+resid, 3=pj -> pairout(f32)
// ---------------------------------------------------------------------------
template <int MODE>
__global__ __launch_bounds__(256) void gemm128b(GArgs g) {
  int e = 0, s0 = 0, Meff = g.M, row0;
  if constexpr (MODE == 3) {
    if ((int)blockIdx.y >= *g.tbl_n) return;
    e = g.tbl_e[blockIdx.y];
    row0 = g.tbl_r0[blockIdx.y];
    s0 = g.eoff[e];
    Meff = g.eoff[e + 1] - s0;
  } else {
    row0 = blockIdx.y * 128;
  }
  const int col0 = blockIdx.x * 128;

  __shared__ __align__(16) unsigned short As[128 * 64];
  __shared__ __align__(16) unsigned short Bs[128 * 64];

  const int tid = threadIdx.x;
  const int lane = tid & 63, w = tid >> 6;
  const int wr = w >> 1, wc = w & 1;
  const int fr = lane & 15, fg = lane >> 4;

  const unsigned short* Bt = g.Bt + (size_t)e * g.Bstride;
  const float* bias = g.bias + (size_t)e * g.biasStride;

  size_t aaddr[4], baddr[4];
#pragma unroll
  for (int i = 0; i < 4; ++i) {
    int pos = i * 256 + tid;
    int r = pos >> 3;
    int c8 = ((pos & 7) ^ (r & 7)) * 8;
    int gr = row0 + r;
    if (gr >= Meff) gr = Meff - 1;
    int srcrow;
    if constexpr (MODE == 3) srcrow = s0 + gr;
    else srcrow = gr;
    aaddr[i] = (size_t)srcrow * g.lda + c8;
    baddr[i] = (size_t)(col0 + r) * g.ldb + c8;
  }

  auto STAGE = [&](int k0) {
#pragma unroll
    for (int i = 0; i < 4; ++i) {
      GLOAD_LDS16(g.A + aaddr[i] + k0, &As[i * 2048 + w * 512]);
      GLOAD_LDS16(Bt + baddr[i] + k0, &Bs[i * 2048 + w * 512]);
    }
  };

  f32x4 acc[4][4] = {};
  const int nt = g.klen / 64;

  for (int t = 0; t < nt; ++t) {
    if (t) __syncthreads();
    STAGE(t * 64);
    __syncthreads();
    b16v8 af[4][2], bf_[4][2];
#pragma unroll
    for (int mi = 0; mi < 4; ++mi) {
      const int ar = wr * 64 + mi * 16 + fr;
      af[mi][0] = *(const b16v8*)&As[swz(ar, fg)];
      af[mi][1] = *(const b16v8*)&As[swz(ar, 4 + fg)];
    }
#pragma unroll
    for (int ni = 0; ni < 4; ++ni) {
      const int br = wc * 64 + ni * 16 + fr;
      bf_[ni][0] = *(const b16v8*)&Bs[swz(br, fg)];
      bf_[ni][1] = *(const b16v8*)&Bs[swz(br, 4 + fg)];
    }
#pragma unroll
    for (int mi = 0; mi < 4; ++mi)
#pragma unroll
      for (int ni = 0; ni < 4; ++ni) {
        acc[mi][ni] = MFMA(af[mi][0], bf_[ni][0], acc[mi][ni]);
        acc[mi][ni] = MFMA(af[mi][1], bf_[ni][1], acc[mi][ni]);
      }
  }

#pragma unroll
  for (int mi = 0; mi < 4; ++mi) {
#pragma unroll
    for (int ni = 0; ni < 4; ++ni) {
#pragma unroll
      for (int rr = 0; rr < 4; ++rr) {
        int row = row0 + wr * 64 + mi * 16 + fg * 4 + rr;
        int col = col0 + wc * 64 + ni * 16 + fr;
        if (row >= Meff) continue;
        float val = acc[mi][ni][rr] + bias[col];
        if constexpr (MODE == 0) {
          int bb = row >> 11, tt = row & (Tc - 1);
          int which = col >> 10, cj = col & (Cc - 1);
          int hd = cj >> 6, d = cj & 63;
          if (which == 0)
            g.outB[(((size_t)(bb * Hc + hd)) * Tc + tt) * Dc + d] = f32_bf16(val);
          else if (which == 1)
            g.outK[(((size_t)(bb * Hc + hd)) * Tc + tt) * Dc + d] = f32_bf16(val);
          else
            g.outV[(((size_t)(bb * Hc + hd)) * Dc + d) * Tc + tt] = f32_bf16(val);
        } else if constexpr (MODE == 1) {
          size_t o = (size_t)row * g.N + col;
          g.outF[o] = val + g.resid[o];
        } else {
          g.outF[(size_t)(s0 + row) * g.N + col] = val;
        }
      }
    }
  }
}

// ---------------------------------------------------------------------------
// fc: 256x256 tile, BK=64, 8 waves (2x4), dbuf 2-phase (r6 loop), swizzled,
// exact 256-stride rowblock table. A gathered via slot_tok; gelu epilogue.
// ---------------------------------------------------------------------------
__global__ __launch_bounds__(512) void gemm256_fc(GArgs g) {
  if ((int)blockIdx.y >= *g.tbl_n) return;
  const int e = g.tbl_e[blockIdx.y];
  const int row0 = g.tbl_r0[blockIdx.y];
  const int s0 = g.eoff[e];
  const int Meff = g.eoff[e + 1] - s0;
  const int col0 = blockIdx.x * 256;

  __shared__ __align__(16) unsigned short As[2][256 * 64];
  __shared__ __align__(16) unsigned short Bs[2][256 * 64];

  const int tid = threadIdx.x;                 // 0..511
  const int lane = tid & 63, w = tid >> 6;     // 8 waves
  const int wr = w >> 2, wc = w & 3;           // 2 x 4 wave grid
  const int fr = lane & 15, fg = lane >> 4;

  const unsigned short* Bt = g.Bt + (size_t)e * g.Bstride;
  const float* bias = g.bias + (size_t)e * g.biasStride;

  size_t aaddr[4], baddr[4];
#pragma unroll
  for (int i = 0; i < 4; ++i) {
    int pos = i * 512 + tid;                   // granule 0..2047
    int r = pos >> 3;                          // LDS row 0..255
    int c8 = ((pos & 7) ^ (r & 7)) * 8;        // swizzled source (elems)
    int gr = row0 + r;
    if (gr >= Meff) gr = Meff - 1;
    int srcrow = g.slot_tok[s0 + gr];
    aaddr[i] = (size_t)srcrow * g.lda + c8;
    baddr[i] = (size_t)(col0 + r) * g.ldb + c8;
  }

  auto STAGE = [&](int buf, int k0) {
#pragma unroll
    for (int i = 0; i < 4; ++i) {
      GLOAD_LDS16(g.A + aaddr[i] + k0, &As[buf][i * 4096 + w * 512]);
      GLOAD_LDS16(Bt + baddr[i] + k0, &Bs[buf][i * 4096 + w * 512]);
    }
  };

  f32x4 acc[8][4] = {};
  const int nt = g.klen / 64;

  STAGE(0, 0);
  SYNC_VM0();
  int cur = 0;

  for (int t = 0; t < nt; ++t) {
    if (t + 1 < nt) STAGE(cur ^ 1, (t + 1) * 64);
    b16v8 bfrag[4][2];
#pragma unroll
    for (int ni = 0; ni < 4; ++ni) {
      const int brow = wc * 64 + ni * 16 + fr;
      bfrag[ni][0] = *(const b16v8*)&Bs[cur][swz(brow, fg)];
      bfrag[ni][1] = *(const b16v8*)&Bs[cur][swz(brow, 4 + fg)];
    }
#pragma unroll
    for (int mi = 0; mi < 8; ++mi) {
      const int arow = wr * 128 + mi * 16 + fr;
      b16v8 a0 = *(const b16v8*)&As[cur][swz(arow, fg)];
      b16v8 a1 = *(const b16v8*)&As[cur][swz(arow, 4 + fg)];
#pragma unroll
      for (int ni = 0; ni < 4; ++ni) {
        acc[mi][ni] = MFMA(a0, bfrag[ni][0], acc[mi][ni]);
        acc[mi][ni] = MFMA(a1, bfrag[ni][1], acc[mi][ni]);
      }
    }
    if (t + 1 < nt) {
      SYNC_VM0();
      cur ^= 1;
    }
  }

#pragma unroll
  for (int mi = 0; mi < 8; ++mi) {
#pragma unroll
    for (int ni = 0; ni < 4; ++ni) {
#pragma unroll
      for (int rr = 0; rr < 4; ++rr) {
        int row = row0 + wr * 128 + mi * 16 + fg * 4 + rr;
        int col = col0 + wc * 64 + ni * 16 + fr;
        if (row >= Meff) continue;
        float val = acc[mi][ni][rr] + bias[col];
        g.outB[(size_t)(s0 + row) * g.N + col] = f32_bf16(gelu_f(val));
      }
    }
  }
}

// ---------------------------------------------------------------------------
// Flash-style causal attention (r13: heavy-first, T14 reg-prefetch).
// ---------------------------------------------------------------------------
__global__ __launch_bounds__(512) void attn_kernel(
    const unsigned short* __restrict__ q, const unsigned short* __restrict__ k,
    const unsigned short* __restrict__ v, unsigned short* __restrict__ y) {
  const int qt = gridDim.x - 1 - blockIdx.x;   // heavy-first
  const int bh = blockIdx.y;
  const int qbase = qt * 128;
  __shared__ __align__(16) unsigned short ldsK[64][72];
  __shared__ __align__(16) unsigned short ldsVT[64][72];     // [d][kv]
  __shared__ __align__(16) unsigned short ldsP[8][16][72];
  const int tid = threadIdx.x, lane = tid & 63, w = tid >> 6;
  const int fr = lane & 15, fg = lane >> 4;
  const size_t base = (size_t)bh * Tc * Dc;
  const int qrow = qbase + w * 16 + fr;
  b16v8 qa0 = *(const b16v8*)(q + base + (size_t)qrow * Dc + fg * 8);
  b16v8 qa1 = *(const b16v8*)(q + base + (size_t)qrow * Dc + 32 + fg * 8);
  float m[4], lsum[4] = {0.f, 0.f, 0.f, 0.f};
#pragma unroll
  for (int r = 0; r < 4; ++r) m[r] = -3.0e38f;
  f32x4 oacc[4] = {};
  constexpr float SC = 0.125f * LOG2E;

  const int sr = tid >> 3, scb = (tid & 7) * 8;
  const int ntile = (qbase + 128) / 64;

  *(uint4*)&ldsK[sr][scb]  = *(const uint4*)(k + base + (size_t)sr * Dc + scb);
  *(uint4*)&ldsVT[sr][scb] = *(const uint4*)(v + base + (size_t)sr * Tc + scb);
  __syncthreads();

  for (int ti = 0; ti < ntile; ++ti) {
    const int kb = ti * 64;
    uint4 kreg, vreg;
    const bool more = (ti + 1 < ntile);
    if (more) {
      const int kn = kb + 64;
      kreg = *(const uint4*)(k + base + (size_t)(kn + sr) * Dc + scb);
      vreg = *(const uint4*)(v + base + (size_t)sr * Tc + kn + scb);
    }

    f32x4 s[4];
#pragma unroll
    for (int ni = 0; ni < 4; ++ni) {
      b16v8 kb0 = *(const b16v8*)&ldsK[ni * 16 + fr][fg * 8];
      b16v8 kb1 = *(const b16v8*)&ldsK[ni * 16 + fr][32 + fg * 8];
      f32x4 z = {};
      z = MFMA(qa0, kb0, z);
      z = MFMA(qa1, kb1, z);
      s[ni] = z;
    }
    const bool diag = (kb + 64 > qbase + w * 16);
#pragma unroll
    for (int ni = 0; ni < 4; ++ni) {
#pragma unroll
      for (int r = 0; r < 4; ++r) {
        float sv = s[ni][r] * SC;
        if (diag) {
          int gq = qbase + w * 16 + fg * 4 + r;
          int kv = kb + ni * 16 + fr;
          if (kv > gq) sv = -3.0e38f;
        }
        s[ni][r] = sv;
      }
    }
#pragma unroll
    for (int r = 0; r < 4; ++r) {
      float mx = fmaxf(fmaxf(s[0][r], s[1][r]), fmaxf(s[2][r], s[3][r]));
#pragma unroll
      for (int msk = 1; msk <= 8; msk <<= 1) mx = fmaxf(mx, __shfl_xor(mx, msk));
      float mnew = fmaxf(m[r], mx);
      float alpha = __builtin_amdgcn_exp2f(m[r] - mnew);
      float psum = 0.f;
#pragma unroll
      for (int ni = 0; ni < 4; ++ni) {
        float pp = __builtin_amdgcn_exp2f(s[ni][r] - mnew);
        s[ni][r] = pp;
        psum += pp;
      }
#pragma unroll
      for (int msk = 1; msk <= 8; msk <<= 1) psum += __shfl_xor(psum, msk);
      lsum[r] = lsum[r] * alpha + psum;
      m[r] = mnew;
#pragma unroll
      for (int ni = 0; ni < 4; ++ni) {
        oacc[ni][r] = oacc[ni][r] * alpha;
        ldsP[w][fg * 4 + r][ni * 16 + fr] = f32_bf16(s[ni][r]);
      }
    }
    asm volatile("s_waitcnt lgkmcnt(0)" ::: "memory");
    __builtin_amdgcn_sched_barrier(0);
    b16v8 pa0 = *(const b16v8*)&ldsP[w][fr][fg * 8];
    b16v8 pa1 = *(const b16v8*)&ldsP[w][fr][32 + fg * 8];
#pragma unroll
    for (int ni = 0; ni < 4; ++ni) {
      b16v8 vb0 = *(const b16v8*)&ldsVT[ni * 16 + fr][fg * 8];
      b16v8 vb1 = *(const b16v8*)&ldsVT[ni * 16 + fr][32 + fg * 8];
      oacc[ni] = MFMA(pa0, vb0, oacc[ni]);
      oacc[ni] = MFMA(pa1, vb1, oacc[ni]);
    }

    if (more) {
      __syncthreads();
      *(uint4*)&ldsK[sr][scb]  = kreg;
      *(uint4*)&ldsVT[sr][scb] = vreg;
      __syncthreads();
    }
  }

  const int bb = bh >> 4, hh = bh & 15;
#pragma unroll
  for (int r = 0; r < 4; ++r) {
    float rl = __builtin_amdgcn_rcpf(lsum[r]);
#pragma unroll
    for (int ni = 0; ni < 4; ++ni) {
      int t = qbase + w * 16 + fg * 4 + r;
      int d = ni * 16 + fr;
      y[((size_t)(bb * Tc + t)) * Cc + hh * Dc + d] = f32_bf16(oacc[ni][r] * rl);
    }
  }
}

// ---------------------------------------------------------------------------
// Deterministic combine: out[n] += p0*pair[s0] + p1*pair[s1]
// ---------------------------------------------------------------------------
__global__ __launch_bounds__(256) void combine_kernel(
    const float* __restrict__ pair, const float* __restrict__ tkp,
    const int* __restrict__ tok2slot, float* __restrict__ out) {
  const int n = blockIdx.x;
  const int c4 = threadIdx.x * 4;
  const int s0 = tok2slot[n * 2], s1 = tok2slot[n * 2 + 1];
  const float p0 = tkp[n * 2], p1 = tkp[n * 2 + 1];
  float4 a = *(const float4*)&pair[(size_t)s0 * Cc + c4];
  float4 b = *(const float4*)&pair[(size_t)s1 * Cc + c4];
  float4 o = *(float4*)&out[(size_t)n * Cc + c4];
  o.x += p0 * a.x + p1 * b.x;
  o.y += p0 * a.y + p1 * b.y;
  o.z += p0 * a.z + p1 * b.z;
  o.w += p0 * a.w + p1 * b.w;
  *(float4*)&out[(size_t)n * Cc + c4] = o;
}

// ---------------------------------------------------------------------------
extern "C" void kernel_launch(void* const* d_in, const int* in_sizes, int n_in,
                              void* d_out, int out_size, void* d_ws, size_t ws_size,
                              hipStream_t stream) {
  const float* x        = (const float*)d_in[0];
  const float* ln1_g    = (const float*)d_in[1];
  const float* ln1_b    = (const float*)d_in[2];
  const float* ln2_g    = (const float*)d_in[3];
  const float* ln2_b    = (const float*)d_in[4];
  const float* attn_w   = (const float*)d_in[5];
  const float* attn_b   = (const float*)d_in[6];
  const float* proj_w   = (const float*)d_in[7];
  const float* proj_b   = (const float*)d_in[8];
  const float* router_w = (const float*)d_in[9];
  const float* fc_w     = (const float*)d_in[10];
  const float* fc_b     = (const float*)d_in[11];
  const float* pj_w     = (const float*)d_in[12];
  const float* pj_b     = (const float*)d_in[13];
  float* out = (float*)d_out;

  char* ws = (char*)d_ws;
  size_t off = 0;
  auto alloc = [&](size_t bytes) -> void* {
    void* p = ws + off;
    off = (off + bytes + 255) & ~(size_t)255;
    return p;
  };
  unsigned short* attn_wT = (unsigned short*)alloc((size_t)3 * Cc * Cc * 2);
  unsigned short* proj_wT = (unsigned short*)alloc((size_t)Cc * Cc * 2);
  unsigned short* fc_wT   = (unsigned short*)alloc((size_t)Ec * HIDc * Cc * 2);
  unsigned short* pj_wT   = (unsigned short*)alloc((size_t)Ec * Cc * HIDc * 2);
  unsigned short* h    = (unsigned short*)alloc((size_t)Nc * Cc * 2);
  unsigned short* qb   = (unsigned short*)alloc((size_t)Nc * Cc * 2);   // [B,H,T,D]
  unsigned short* kbuf = (unsigned short*)alloc((size_t)Nc * Cc * 2);   // [B,H,T,D]
  unsigned short* vbuf = (unsigned short*)alloc((size_t)Nc * Cc * 2);   // [B,H,D,T]
  unsigned short* ybuf = (unsigned short*)alloc((size_t)Nc * Cc * 2);   // [N,C]
  unsigned short* he   = (unsigned short*)alloc((size_t)NPAIR * HIDc * 2);
  float* pairout = (float*)alloc((size_t)NPAIR * Cc * 4);
  int*   tki     = (int*)alloc((size_t)Nc * 2 * 4);
  float* tkp     = (float*)alloc((size_t)Nc * 2 * 4);
  int*   counts  = (int*)alloc(Ec * 4);
  int*   eoff    = (int*)alloc((Ec + 1) * 4);
  int*   cursor  = (int*)alloc(Ec * 4);
  int*   slot_tok= (int*)alloc((size_t)NPAIR * 4);
  int*   tok2slot= (int*)alloc((size_t)Nc * 2 * 4);
  int*   tbl_e   = (int*)alloc(NRBMAX * 4);
  int*   tbl_r0  = (int*)alloc(NRBMAX * 4);
  int*   tbl_n   = (int*)alloc(4);
  int*   tbl2_e  = (int*)alloc(NRB2MAX * 4);
  int*   tbl2_r0 = (int*)alloc(NRB2MAX * 4);
  int*   tbl2_n  = (int*)alloc(4);
  (void)ws_size; (void)in_sizes; (void)n_in; (void)out_size;

  // 0) weight pre-transpose/convert (64x64 tiles)
  convT_kernel<<<dim3(3 * Cc / 64, Cc / 64, 1), 256, 0, stream>>>(attn_w, attn_wT, Cc, 3 * Cc);
  convT_kernel<<<dim3(Cc / 64, Cc / 64, 1), 256, 0, stream>>>(proj_w, proj_wT, Cc, Cc);
  convT_kernel<<<dim3(HIDc / 64, Cc / 64, Ec), 256, 0, stream>>>(fc_w, fc_wT, Cc, HIDc);
  convT_kernel<<<dim3(Cc / 64, HIDc / 64, Ec), 256, 0, stream>>>(pj_w, pj_wT, HIDc, Cc);

  // 1) LN1
  ln1_kernel<<<Nc, 256, 0, stream>>>(x, ln1_g, ln1_b, h);

  // 2) QKV GEMM -> q/k [B,H,T,D], v^T [B,H,D,T]
  {
    GArgs a = {};
    a.A = h; a.Bt = attn_wT; a.bias = attn_b;
    a.M = Nc; a.N = 3 * Cc; a.K = Cc; a.lda = Cc; a.ldb = Cc; a.klen = Cc;
    a.outB = qb; a.outK = kbuf; a.outV = vbuf;
    gemm128b<0><<<dim3(3 * Cc / 128, Nc / 128, 1), 256, 0, stream>>>(a);
  }

  // 3) causal attention -> y [N,C] bf16 (heavy-first)
  attn_kernel<<<dim3(Tc / 128, Bc * Hc), 512, 0, stream>>>(qb, kbuf, vbuf, ybuf);

  // 4) proj + residual -> d_out (f32)
  {
    GArgs p = {};
    p.A = ybuf; p.Bt = proj_wT; p.bias = proj_b;
    p.M = Nc; p.N = Cc; p.K = Cc; p.lda = Cc; p.ldb = Cc; p.klen = Cc;
    p.outF = out; p.resid = x;
    gemm128b<1><<<dim3(Cc / 128, Nc / 128, 1), 256, 0, stream>>>(p);
  }

  // 5) LN2 + router -> h (bf16), top-2
  ln2_router_kernel<<<Nc, 256, 0, stream>>>(out, ln2_g, ln2_b, router_w, h, tki, tkp);

  // 6) routing lists + rowblock tables
  hipMemsetAsync(counts, 0, Ec * sizeof(int), stream);
  count_kernel<<<(Nc + 255) / 256, 256, 0, stream>>>(tki, counts);
  scan_kernel<<<1, 64, 0, stream>>>(counts, eoff, cursor, tbl_e, tbl_r0, tbl_n,
                                    tbl2_e, tbl2_r0, tbl2_n);
  assign_kernel<<<(Nc + 255) / 256, 256, 0, stream>>>(tki, cursor, slot_tok, tok2slot);

  // 7) fc -> he [NPAIR][HID] bf16 w/ GELU (256^2 2-phase, exact 256-table)
  {
    GArgs f = {};
    f.A = h; f.Bt = fc_wT; f.bias = fc_b;
    f.M = Nc; f.N = HIDc; f.K = Cc; f.lda = Cc; f.ldb = Cc; f.klen = Cc;
    f.Bstride = (size_t)HIDc * Cc; f.biasStride = HIDc;
    f.eoff = eoff; f.slot_tok = slot_tok;
    f.tbl_e = tbl2_e; f.tbl_r0 = tbl2_r0; f.tbl_n = tbl2_n;
    f.outB = he;
    gemm256_fc<<<dim3(HIDc / 256, NRB2MAX, 1), 512, 0, stream>>>(f);
  }

  // 8) pj (single K pass, 128^2 r8 structure) -> pairout [NPAIR][C] f32
  {
    GArgs pj = {};
    pj.A = he; pj.Bt = pj_wT; pj.bias = pj_b;
    pj.M = Nc; pj.N = Cc; pj.K = HIDc; pj.lda = HIDc; pj.ldb = HIDc; pj.klen = HIDc;
    pj.Bstride = (size_t)Cc * HIDc; pj.biasStride = Cc;
    pj.eoff = eoff;
    pj.tbl_e = tbl_e; pj.tbl_r0 = tbl_r0; pj.tbl_n = tbl_n;
    pj.outF = pairout;
    gemm128b<3><<<dim3(Cc / 128, NRBMAX, 1), 256, 0, stream>>>(pj);
  }

  // 9) deterministic combine into d_out
  combine_kernel<<<Nc, 256, 0, stream>>>(pairout, tkp, tok2slot, out);
}

// Round 15
// 615.861 us; speedup vs baseline: 1.0486x; 1.0486x over previous
//
#include <hip/hip_runtime.h>
#include <math.h>

// ---------------------------------------------------------------------------
// Fused transformer block w/ MoE (B=2,T=2048,C=1024,H=16,D=64,E=8,topK=2)
// Round 15: r13 restored (best: 616us; r8 GEMM everywhere) + attn exact
// no-growth fast path (skip rescale when no row max grows) + bf16 pairout.
// ---------------------------------------------------------------------------

typedef __bf16 b16v8 __attribute__((ext_vector_type(8)));
typedef float f32x4 __attribute__((ext_vector_type(4)));

#define MFMA(a, b, c) __builtin_amdgcn_mfma_f32_16x16x32_bf16(a, b, c, 0, 0, 0)

#define GLOAD_LDS16(g, l)                                          \
  __builtin_amdgcn_global_load_lds(                                \
      (const __attribute__((address_space(1))) void*)(g),          \
      (__attribute__((address_space(3))) void*)(l), 16, 0, 0)

constexpr int Bc = 2, Tc = 2048, Cc = 1024, Hc = 16, Dc = 64;
constexpr int Nc = Bc * Tc;       // 4096 tokens
constexpr int HIDc = 4096;        // 4*C
constexpr int Ec = 8;
constexpr int NPAIR = Nc * 2;     // 8192
constexpr int NRBMAX = NPAIR / 128 + Ec;  // 72
constexpr float LOG2E = 1.4426950408889634f;

__device__ inline unsigned short f32_bf16(float f) {
  union { float f; unsigned u; } x; x.f = f;
  unsigned r = x.u + 0x7fffu + ((x.u >> 16) & 1u);   // RNE
  return (unsigned short)(r >> 16);
}

__device__ inline float bf16_f32(unsigned short u) {
  union { unsigned u; float f; } x; x.u = ((unsigned)u) << 16;
  return x.f;
}

// gelu(x) = x * sigmoid(1.595769122*(x+0.044715x^3)); exp2-domain
__device__ inline float gelu_f(float x) {
  float t = 2.3021188f * x * (1.f + 0.044715f * x * x);
  float e = __builtin_amdgcn_exp2f(-t);
  return x * __builtin_amdgcn_rcpf(1.f + e);
}

// LDS element index for [row][64-elem] rows with 16B-granule XOR swizzle.
__device__ inline int swz(int row, int g) {
  return row * 64 + ((g ^ (row & 7)) * 8);
}

// ---------------------------------------------------------------------------
// Transpose+convert: src f32 [batch][K][N] -> dst bf16 [batch][N][K]
// 64x64 tile, float4 reads, LDS [64][65], ushort4 writes.
// ---------------------------------------------------------------------------
__global__ __launch_bounds__(256) void convT_kernel(
    const float* __restrict__ src, unsigned short* __restrict__ dst,
    int K, int N) {
  const size_t sb = (size_t)blockIdx.z * K * N;
  const int n0 = blockIdx.x * 64, k0 = blockIdx.y * 64;
  __shared__ float t[64][65];
  const int tid = threadIdx.x;
#pragma unroll
  for (int j = 0; j < 4; ++j) {
    int idx = j * 256 + tid;
    int r = idx >> 4;
    int c4 = (idx & 15) << 2;
    float4 v = *(const float4*)&src[sb + (size_t)(k0 + r) * N + n0 + c4];
    t[r][c4] = v.x; t[r][c4 + 1] = v.y; t[r][c4 + 2] = v.z; t[r][c4 + 3] = v.w;
  }
  __syncthreads();
#pragma unroll
  for (int j = 0; j < 4; ++j) {
    int idx = j * 256 + tid;
    int n = idx >> 4;
    int k4 = (idx & 15) << 2;
    ushort4 o;
    o.x = f32_bf16(t[k4][n]);
    o.y = f32_bf16(t[k4 + 1][n]);
    o.z = f32_bf16(t[k4 + 2][n]);
    o.w = f32_bf16(t[k4 + 3][n]);
    *(ushort4*)&dst[sb + (size_t)(n0 + n) * K + k0 + k4] = o;
  }
}

// ---------------------------------------------------------------------------
// LayerNorm (f32 in -> bf16 out).
// ---------------------------------------------------------------------------
__global__ __launch_bounds__(256) void ln1_kernel(
    const float* __restrict__ x, const float* __restrict__ g,
    const float* __restrict__ b, unsigned short* __restrict__ out) {
  const int row = blockIdx.x;
  const int tid = threadIdx.x;
  const float* xr = x + (size_t)row * Cc;
  float v[4]; float s = 0.f, q = 0.f;
#pragma unroll
  for (int j = 0; j < 4; ++j) { v[j] = xr[tid + j * 256]; s += v[j]; q += v[j] * v[j]; }
#pragma unroll
  for (int m = 1; m <= 32; m <<= 1) { s += __shfl_xor(s, m); q += __shfl_xor(q, m); }
  __shared__ float red[2][4];
  const int w = tid >> 6;
  if ((tid & 63) == 0) { red[0][w] = s; red[1][w] = q; }
  __syncthreads();
  s = red[0][0] + red[0][1] + red[0][2] + red[0][3];
  q = red[1][0] + red[1][1] + red[1][2] + red[1][3];
  const float mean = s * (1.f / Cc);
  const float var = q * (1.f / Cc) - mean * mean;
  const float rstd = rsqrtf(var + 1e-5f);
#pragma unroll
  for (int j = 0; j < 4; ++j) {
    int c = tid + j * 256;
    out[(size_t)row * Cc + c] = f32_bf16((v[j] - mean) * rstd * g[c] + b[c]);
  }
}

// ---------------------------------------------------------------------------
// LN2 + router (f32 router math).
// ---------------------------------------------------------------------------
__global__ __launch_bounds__(256) void ln2_router_kernel(
    const float* __restrict__ x, const float* __restrict__ g,
    const float* __restrict__ b, const float* __restrict__ rw,
    unsigned short* __restrict__ out, int* __restrict__ tki, float* __restrict__ tkp) {
  const int row = blockIdx.x;
  const int tid = threadIdx.x;
  const float* xr = x + (size_t)row * Cc;
  float v[4]; float s = 0.f, q = 0.f;
#pragma unroll
  for (int j = 0; j < 4; ++j) { v[j] = xr[tid + j * 256]; s += v[j]; q += v[j] * v[j]; }
#pragma unroll
  for (int m = 1; m <= 32; m <<= 1) { s += __shfl_xor(s, m); q += __shfl_xor(q, m); }
  __shared__ float red[2][4];
  const int w = tid >> 6;
  if ((tid & 63) == 0) { red[0][w] = s; red[1][w] = q; }
  __syncthreads();
  s = red[0][0] + red[0][1] + red[0][2] + red[0][3];
  q = red[1][0] + red[1][1] + red[1][2] + red[1][3];
  const float mean = s * (1.f / Cc);
  const float var = q * (1.f / Cc) - mean * mean;
  const float rstd = rsqrtf(var + 1e-5f);
  float lg[8] = {0.f, 0.f, 0.f, 0.f, 0.f, 0.f, 0.f, 0.f};
#pragma unroll
  for (int j = 0; j < 4; ++j) {
    int c = tid + j * 256;
    float nv = (v[j] - mean) * rstd * g[c] + b[c];
    out[(size_t)row * Cc + c] = f32_bf16(nv);
    const float* rwc = rw + c * 8;
#pragma unroll
    for (int e = 0; e < 8; ++e) lg[e] += nv * rwc[e];
  }
#pragma unroll
  for (int m = 1; m <= 32; m <<= 1) {
#pragma unroll
    for (int e = 0; e < 8; ++e) lg[e] += __shfl_xor(lg[e], m);
  }
  __shared__ float rl[4][8];
  if ((tid & 63) == 0) {
#pragma unroll
    for (int e = 0; e < 8; ++e) rl[w][e] = lg[e];
  }
  __syncthreads();
  if (tid == 0) {
    float L[8];
#pragma unroll
    for (int e = 0; e < 8; ++e) L[e] = rl[0][e] + rl[1][e] + rl[2][e] + rl[3][e];
    int i1 = 0;
    for (int e = 1; e < 8; ++e) if (L[e] > L[i1]) i1 = e;
    int i2 = (i1 == 0) ? 1 : 0;
    for (int e = 0; e < 8; ++e) if (e != i1 && L[e] > L[i2]) i2 = e;
    float e2 = expf(L[i2] - L[i1]);
    float inv = 1.f / (1.f + e2);
    tki[row * 2] = i1; tki[row * 2 + 1] = i2;
    tkp[row * 2] = inv; tkp[row * 2 + 1] = e2 * inv;
  }
}

// ---------------------------------------------------------------------------
// Routing: counts -> offsets + rowblock table -> slot assignment.
// ---------------------------------------------------------------------------
__global__ __launch_bounds__(256) void count_kernel(
    const int* __restrict__ tki, int* __restrict__ counts) {
  int n = blockIdx.x * 256 + threadIdx.x;
  if (n >= Nc) return;
  atomicAdd(&counts[tki[n * 2]], 1);
  atomicAdd(&counts[tki[n * 2 + 1]], 1);
}

__global__ void scan_kernel(const int* __restrict__ counts,
                            int* __restrict__ eoff, int* __restrict__ cursor,
                            int* __restrict__ tbl_e, int* __restrict__ tbl_r0,
                            int* __restrict__ tbl_n) {
  if (threadIdx.x == 0 && blockIdx.x == 0) {
    int s = 0, nb = 0;
    for (int e = 0; e < Ec; ++e) {
      eoff[e] = s; cursor[e] = s;
      for (int r = 0; r < counts[e]; r += 128) {
        tbl_e[nb] = e; tbl_r0[nb] = r; ++nb;
      }
      s += counts[e];
    }
    eoff[Ec] = s;
    *tbl_n = nb;
  }
}

__global__ __launch_bounds__(256) void assign_kernel(
    const int* __restrict__ tki, int* __restrict__ cursor,
    int* __restrict__ slot_tok, int* __restrict__ tok2slot) {
  int n = blockIdx.x * 256 + threadIdx.x;
  if (n >= Nc) return;
#pragma unroll
  for (int kk = 0; kk < 2; ++kk) {
    int e = tki[n * 2 + kk];
    int slot = atomicAdd(&cursor[e], 1);
    slot_tok[slot] = n;
    tok2slot[n * 2 + kk] = slot;
  }
}

// ---------------------------------------------------------------------------
struct GArgs {
  const unsigned short* A;    // bf16 [M][lda]
  const unsigned short* Bt;   // bf16 [N][ldb] (+ e*Bstride)
  const float* bias;          // f32 [N]      (+ e*biasStride)
  int M, N, K, lda, ldb, klen;
  size_t Bstride; int biasStride;
  const int* eoff;            // [E+1] (MODE 2/3)
  const int* slot_tok;        // (MODE 2)
  const int* tbl_e;           // rowblock table (MODE 2/3)
  const int* tbl_r0;
  const int* tbl_n;
  float* outF;                // MODE 1: out
  const float* resid;         // MODE 1
  unsigned short* outB;       // MODE 2: he ; MODE 3: pairout(bf16); MODE 0: q
  unsigned short* outK;       // MODE 0: k
  unsigned short* outV;       // MODE 0: v^T [B,H,D,T]
};

// ---------------------------------------------------------------------------
// 128x128 tile, BK=64, 4 waves (2x2), SINGLE buffer, XOR granule swizzle.
// 32 KiB LDS -> ~5 blocks/CU (r8 structure, session best).
// MODE: 0=QKV scatter, 1=proj+resid, 2=fc gather+gelu, 3=pj -> pairout(bf16)
// ---------------------------------------------------------------------------
template <int MODE>
__global__ __launch_bounds__(256) void gemm128b(GArgs g) {
  int e = 0, s0 = 0, Meff = g.M, row0;
  if constexpr (MODE == 2 || MODE == 3) {
    if ((int)blockIdx.y >= *g.tbl_n) return;
    e = g.tbl_e[blockIdx.y];
    row0 = g.tbl_r0[blockIdx.y];
    s0 = g.eoff[e];
    Meff = g.eoff[e + 1] - s0;
  } else {
    row0 = blockIdx.y * 128;
  }
  const int col0 = blockIdx.x * 128;

  __shared__ __align__(16) unsigned short As[128 * 64];
  __shared__ __align__(16) unsigned short Bs[128 * 64];

  const int tid = threadIdx.x;
  const int lane = tid & 63, w = tid >> 6;
  const int wr = w >> 1, wc = w & 1;
  const int fr = lane & 15, fg = lane >> 4;

  const unsigned short* Bt = g.Bt + (size_t)e * g.Bstride;
  const float* bias = g.bias + (size_t)e * g.biasStride;

  // LDS dest linear (gload_lds); GLOBAL source granule pre-swizzled (#21).
  size_t aaddr[4], baddr[4];
#pragma unroll
  for (int i = 0; i < 4; ++i) {
    int pos = i * 256 + tid;
    int r = pos >> 3;
    int c8 = ((pos & 7) ^ (r & 7)) * 8;
    int gr = row0 + r;
    if (gr >= Meff) gr = Meff - 1;
    int srcrow;
    if constexpr (MODE == 2) srcrow = g.slot_tok[s0 + gr];
    else if constexpr (MODE == 3) srcrow = s0 + gr;
    else srcrow = gr;
    aaddr[i] = (size_t)srcrow * g.lda + c8;
    baddr[i] = (size_t)(col0 + r) * g.ldb + c8;
  }

  auto STAGE = [&](int k0) {
#pragma unroll
    for (int i = 0; i < 4; ++i) {
      GLOAD_LDS16(g.A + aaddr[i] + k0, &As[i * 2048 + w * 512]);
      GLOAD_LDS16(Bt + baddr[i] + k0, &Bs[i * 2048 + w * 512]);
    }
  };

  f32x4 acc[4][4] = {};
  const int nt = g.klen / 64;

  for (int t = 0; t < nt; ++t) {
    if (t) __syncthreads();
    STAGE(t * 64);
    __syncthreads();
    b16v8 af[4][2], bf_[4][2];
#pragma unroll
    for (int mi = 0; mi < 4; ++mi) {
      const int ar = wr * 64 + mi * 16 + fr;
      af[mi][0] = *(const b16v8*)&As[swz(ar, fg)];
      af[mi][1] = *(const b16v8*)&As[swz(ar, 4 + fg)];
    }
#pragma unroll
    for (int ni = 0; ni < 4; ++ni) {
      const int br = wc * 64 + ni * 16 + fr;
      bf_[ni][0] = *(const b16v8*)&Bs[swz(br, fg)];
      bf_[ni][1] = *(const b16v8*)&Bs[swz(br, 4 + fg)];
    }
#pragma unroll
    for (int mi = 0; mi < 4; ++mi)
#pragma unroll
      for (int ni = 0; ni < 4; ++ni) {
        acc[mi][ni] = MFMA(af[mi][0], bf_[ni][0], acc[mi][ni]);
        acc[mi][ni] = MFMA(af[mi][1], bf_[ni][1], acc[mi][ni]);
      }
  }

#pragma unroll
  for (int mi = 0; mi < 4; ++mi) {
#pragma unroll
    for (int ni = 0; ni < 4; ++ni) {
#pragma unroll
      for (int rr = 0; rr < 4; ++rr) {
        int row = row0 + wr * 64 + mi * 16 + fg * 4 + rr;
        int col = col0 + wc * 64 + ni * 16 + fr;
        if (row >= Meff) continue;
        float val = acc[mi][ni][rr] + bias[col];
        if constexpr (MODE == 0) {
          int bb = row >> 11, tt = row & (Tc - 1);
          int which = col >> 10, cj = col & (Cc - 1);
          int hd = cj >> 6, d = cj & 63;
          if (which == 0)
            g.outB[(((size_t)(bb * Hc + hd)) * Tc + tt) * Dc + d] = f32_bf16(val);
          else if (which == 1)
            g.outK[(((size_t)(bb * Hc + hd)) * Tc + tt) * Dc + d] = f32_bf16(val);
          else
            g.outV[(((size_t)(bb * Hc + hd)) * Dc + d) * Tc + tt] = f32_bf16(val);
        } else if constexpr (MODE == 1) {
          size_t o = (size_t)row * g.N + col;
          g.outF[o] = val + g.resid[o];
        } else if constexpr (MODE == 2) {
          g.outB[(size_t)(s0 + row) * g.N + col] = f32_bf16(gelu_f(val));
        } else {
          g.outB[(size_t)(s0 + row) * g.N + col] = f32_bf16(val);
        }
      }
    }
  }
}

// ---------------------------------------------------------------------------
// Flash-style causal attention. 8 waves, 128 q-rows, KV tile 64.
// Heavy-first dispatch; T14 reg-prefetch; exact no-growth fast path (skip
// rescale when no row's tile max exceeds the running max, wave-uniform).
// ---------------------------------------------------------------------------
__global__ __launch_bounds__(512) void attn_kernel(
    const unsigned short* __restrict__ q, const unsigned short* __restrict__ k,
    const unsigned short* __restrict__ v, unsigned short* __restrict__ y) {
  const int qt = gridDim.x - 1 - blockIdx.x;   // heavy-first
  const int bh = blockIdx.y;
  const int qbase = qt * 128;
  __shared__ __align__(16) unsigned short ldsK[64][72];
  __shared__ __align__(16) unsigned short ldsVT[64][72];     // [d][kv]
  __shared__ __align__(16) unsigned short ldsP[8][16][72];
  const int tid = threadIdx.x, lane = tid & 63, w = tid >> 6;
  const int fr = lane & 15, fg = lane >> 4;
  const size_t base = (size_t)bh * Tc * Dc;
  const int qrow = qbase + w * 16 + fr;
  b16v8 qa0 = *(const b16v8*)(q + base + (size_t)qrow * Dc + fg * 8);
  b16v8 qa1 = *(const b16v8*)(q + base + (size_t)qrow * Dc + 32 + fg * 8);
  float m[4], lsum[4] = {0.f, 0.f, 0.f, 0.f};
#pragma unroll
  for (int r = 0; r < 4; ++r) m[r] = -3.0e38f;
  f32x4 oacc[4] = {};
  constexpr float SC = 0.125f * LOG2E;

  const int sr = tid >> 3, scb = (tid & 7) * 8;
  const int ntile = (qbase + 128) / 64;

  *(uint4*)&ldsK[sr][scb]  = *(const uint4*)(k + base + (size_t)sr * Dc + scb);
  *(uint4*)&ldsVT[sr][scb] = *(const uint4*)(v + base + (size_t)sr * Tc + scb);
  __syncthreads();

  for (int ti = 0; ti < ntile; ++ti) {
    const int kb = ti * 64;
    uint4 kreg, vreg;
    const bool more = (ti + 1 < ntile);
    if (more) {
      const int kn = kb + 64;
      kreg = *(const uint4*)(k + base + (size_t)(kn + sr) * Dc + scb);
      vreg = *(const uint4*)(v + base + (size_t)sr * Tc + kn + scb);
    }

    f32x4 s[4];
#pragma unroll
    for (int ni = 0; ni < 4; ++ni) {
      b16v8 kb0 = *(const b16v8*)&ldsK[ni * 16 + fr][fg * 8];
      b16v8 kb1 = *(const b16v8*)&ldsK[ni * 16 + fr][32 + fg * 8];
      f32x4 z = {};
      z = MFMA(qa0, kb0, z);
      z = MFMA(qa1, kb1, z);
      s[ni] = z;
    }
    const bool diag = (kb + 64 > qbase + w * 16);
#pragma unroll
    for (int ni = 0; ni < 4; ++ni) {
#pragma unroll
      for (int r = 0; r < 4; ++r) {
        float sv = s[ni][r] * SC;
        if (diag) {
          int gq = qbase + w * 16 + fg * 4 + r;
          int kv = kb + ni * 16 + fr;
          if (kv > gq) sv = -3.0e38f;
        }
        s[ni][r] = sv;
      }
    }
    // tile maxima per row + wave-uniform growth check
    float mx[4];
    bool grow = false;
#pragma unroll
    for (int r = 0; r < 4; ++r) {
      float t = fmaxf(fmaxf(s[0][r], s[1][r]), fmaxf(s[2][r], s[3][r]));
#pragma unroll
      for (int msk = 1; msk <= 8; msk <<= 1) t = fmaxf(t, __shfl_xor(t, msk));
      mx[r] = t;
      grow = grow || (t > m[r]);
    }
    if (__any(grow)) {
      // slow path: full online-softmax rescale
#pragma unroll
      for (int r = 0; r < 4; ++r) {
        float mnew = fmaxf(m[r], mx[r]);
        float alpha = __builtin_amdgcn_exp2f(m[r] - mnew);
        float psum = 0.f;
#pragma unroll
        for (int ni = 0; ni < 4; ++ni) {
          float pp = __builtin_amdgcn_exp2f(s[ni][r] - mnew);
          s[ni][r] = pp;
          psum += pp;
        }
#pragma unroll
        for (int msk = 1; msk <= 8; msk <<= 1) psum += __shfl_xor(psum, msk);
        lsum[r] = lsum[r] * alpha + psum;
        m[r] = mnew;
#pragma unroll
        for (int ni = 0; ni < 4; ++ni) {
          oacc[ni][r] = oacc[ni][r] * alpha;
          ldsP[w][fg * 4 + r][ni * 16 + fr] = f32_bf16(s[ni][r]);
        }
      }
    } else {
      // fast path: no new max anywhere in the wave -> alpha == 1 exactly
#pragma unroll
      for (int r = 0; r < 4; ++r) {
        float psum = 0.f;
#pragma unroll
        for (int ni = 0; ni < 4; ++ni) {
          float pp = __builtin_amdgcn_exp2f(s[ni][r] - m[r]);
          s[ni][r] = pp;
          psum += pp;
        }
#pragma unroll
        for (int msk = 1; msk <= 8; msk <<= 1) psum += __shfl_xor(psum, msk);
        lsum[r] += psum;
#pragma unroll
        for (int ni = 0; ni < 4; ++ni)
          ldsP[w][fg * 4 + r][ni * 16 + fr] = f32_bf16(s[ni][r]);
      }
    }
    asm volatile("s_waitcnt lgkmcnt(0)" ::: "memory");
    __builtin_amdgcn_sched_barrier(0);
    b16v8 pa0 = *(const b16v8*)&ldsP[w][fr][fg * 8];
    b16v8 pa1 = *(const b16v8*)&ldsP[w][fr][32 + fg * 8];
#pragma unroll
    for (int ni = 0; ni < 4; ++ni) {
      b16v8 vb0 = *(const b16v8*)&ldsVT[ni * 16 + fr][fg * 8];
      b16v8 vb1 = *(const b16v8*)&ldsVT[ni * 16 + fr][32 + fg * 8];
      oacc[ni] = MFMA(pa0, vb0, oacc[ni]);
      oacc[ni] = MFMA(pa1, vb1, oacc[ni]);
    }

    if (more) {
      __syncthreads();
      *(uint4*)&ldsK[sr][scb]  = kreg;
      *(uint4*)&ldsVT[sr][scb] = vreg;
      __syncthreads();
    }
  }

  const int bb = bh >> 4, hh = bh & 15;
#pragma unroll
  for (int r = 0; r < 4; ++r) {
    float rl = __builtin_amdgcn_rcpf(lsum[r]);
#pragma unroll
    for (int ni = 0; ni < 4; ++ni) {
      int t = qbase + w * 16 + fg * 4 + r;
      int d = ni * 16 + fr;
      y[((size_t)(bb * Tc + t)) * Cc + hh * Dc + d] = f32_bf16(oacc[ni][r] * rl);
    }
  }
}

// ---------------------------------------------------------------------------
// Deterministic combine (bf16 pairout): out[n] += p0*pair[s0] + p1*pair[s1]
// ---------------------------------------------------------------------------
__global__ __launch_bounds__(256) void combine_kernel(
    const unsigned short* __restrict__ pair, const float* __restrict__ tkp,
    const int* __restrict__ tok2slot, float* __restrict__ out) {
  const int n = blockIdx.x;
  const int c4 = threadIdx.x * 4;
  const int s0 = tok2slot[n * 2], s1 = tok2slot[n * 2 + 1];
  const float p0 = tkp[n * 2], p1 = tkp[n * 2 + 1];
  ushort4 a = *(const ushort4*)&pair[(size_t)s0 * Cc + c4];
  ushort4 b = *(const ushort4*)&pair[(size_t)s1 * Cc + c4];
  float4 o = *(float4*)&out[(size_t)n * Cc + c4];
  o.x += p0 * bf16_f32(a.x) + p1 * bf16_f32(b.x);
  o.y += p0 * bf16_f32(a.y) + p1 * bf16_f32(b.y);
  o.z += p0 * bf16_f32(a.z) + p1 * bf16_f32(b.z);
  o.w += p0 * bf16_f32(a.w) + p1 * bf16_f32(b.w);
  *(float4*)&out[(size_t)n * Cc + c4] = o;
}

// ---------------------------------------------------------------------------
extern "C" void kernel_launch(void* const* d_in, const int* in_sizes, int n_in,
                              void* d_out, int out_size, void* d_ws, size_t ws_size,
                              hipStream_t stream) {
  const float* x        = (const float*)d_in[0];
  const float* ln1_g    = (const float*)d_in[1];
  const float* ln1_b    = (const float*)d_in[2];
  const float* ln2_g    = (const float*)d_in[3];
  const float* ln2_b    = (const float*)d_in[4];
  const float* attn_w   = (const float*)d_in[5];
  const float* attn_b   = (const float*)d_in[6];
  const float* proj_w   = (const float*)d_in[7];
  const float* proj_b   = (const float*)d_in[8];
  const float* router_w = (const float*)d_in[9];
  const float* fc_w     = (const float*)d_in[10];
  const float* fc_b     = (const float*)d_in[11];
  const float* pj_w     = (const float*)d_in[12];
  const float* pj_b     = (const float*)d_in[13];
  float* out = (float*)d_out;

  char* ws = (char*)d_ws;
  size_t off = 0;
  auto alloc = [&](size_t bytes) -> void* {
    void* p = ws + off;
    off = (off + bytes + 255) & ~(size_t)255;
    return p;
  };
  unsigned short* attn_wT = (unsigned short*)alloc((size_t)3 * Cc * Cc * 2);
  unsigned short* proj_wT = (unsigned short*)alloc((size_t)Cc * Cc * 2);
  unsigned short* fc_wT   = (unsigned short*)alloc((size_t)Ec * HIDc * Cc * 2);
  unsigned short* pj_wT   = (unsigned short*)alloc((size_t)Ec * Cc * HIDc * 2);
  unsigned short* h    = (unsigned short*)alloc((size_t)Nc * Cc * 2);
  unsigned short* qb   = (unsigned short*)alloc((size_t)Nc * Cc * 2);   // [B,H,T,D]
  unsigned short* kbuf = (unsigned short*)alloc((size_t)Nc * Cc * 2);   // [B,H,T,D]
  unsigned short* vbuf = (unsigned short*)alloc((size_t)Nc * Cc * 2);   // [B,H,D,T]
  unsigned short* ybuf = (unsigned short*)alloc((size_t)Nc * Cc * 2);   // [N,C]
  unsigned short* he   = (unsigned short*)alloc((size_t)NPAIR * HIDc * 2);
  unsigned short* pairout = (unsigned short*)alloc((size_t)NPAIR * Cc * 2);
  int*   tki     = (int*)alloc((size_t)Nc * 2 * 4);
  float* tkp     = (float*)alloc((size_t)Nc * 2 * 4);
  int*   counts  = (int*)alloc(Ec * 4);
  int*   eoff    = (int*)alloc((Ec + 1) * 4);
  int*   cursor  = (int*)alloc(Ec * 4);
  int*   slot_tok= (int*)alloc((size_t)NPAIR * 4);
  int*   tok2slot= (int*)alloc((size_t)Nc * 2 * 4);
  int*   tbl_e   = (int*)alloc(NRBMAX * 4);
  int*   tbl_r0  = (int*)alloc(NRBMAX * 4);
  int*   tbl_n   = (int*)alloc(4);
  (void)ws_size; (void)in_sizes; (void)n_in; (void)out_size;

  // 0) weight pre-transpose/convert (64x64 tiles)
  convT_kernel<<<dim3(3 * Cc / 64, Cc / 64, 1), 256, 0, stream>>>(attn_w, attn_wT, Cc, 3 * Cc);
  convT_kernel<<<dim3(Cc / 64, Cc / 64, 1), 256, 0, stream>>>(proj_w, proj_wT, Cc, Cc);
  convT_kernel<<<dim3(HIDc / 64, Cc / 64, Ec), 256, 0, stream>>>(fc_w, fc_wT, Cc, HIDc);
  convT_kernel<<<dim3(Cc / 64, HIDc / 64, Ec), 256, 0, stream>>>(pj_w, pj_wT, HIDc, Cc);

  // 1) LN1
  ln1_kernel<<<Nc, 256, 0, stream>>>(x, ln1_g, ln1_b, h);

  // 2) QKV GEMM -> q/k [B,H,T,D], v^T [B,H,D,T]
  {
    GArgs a = {};
    a.A = h; a.Bt = attn_wT; a.bias = attn_b;
    a.M = Nc; a.N = 3 * Cc; a.K = Cc; a.lda = Cc; a.ldb = Cc; a.klen = Cc;
    a.outB = qb; a.outK = kbuf; a.outV = vbuf;
    gemm128b<0><<<dim3(3 * Cc / 128, Nc / 128, 1), 256, 0, stream>>>(a);
  }

  // 3) causal attention -> y [N,C] bf16 (heavy-first)
  attn_kernel<<<dim3(Tc / 128, Bc * Hc), 512, 0, stream>>>(qb, kbuf, vbuf, ybuf);

  // 4) proj + residual -> d_out (f32)
  {
    GArgs p = {};
    p.A = ybuf; p.Bt = proj_wT; p.bias = proj_b;
    p.M = Nc; p.N = Cc; p.K = Cc; p.lda = Cc; p.ldb = Cc; p.klen = Cc;
    p.outF = out; p.resid = x;
    gemm128b<1><<<dim3(Cc / 128, Nc / 128, 1), 256, 0, stream>>>(p);
  }

  // 5) LN2 + router -> h (bf16), top-2
  ln2_router_kernel<<<Nc, 256, 0, stream>>>(out, ln2_g, ln2_b, router_w, h, tki, tkp);

  // 6) routing lists (slot-compacted pairs) + rowblock table
  hipMemsetAsync(counts, 0, Ec * sizeof(int), stream);
  count_kernel<<<(Nc + 255) / 256, 256, 0, stream>>>(tki, counts);
  scan_kernel<<<1, 64, 0, stream>>>(counts, eoff, cursor, tbl_e, tbl_r0, tbl_n);
  assign_kernel<<<(Nc + 255) / 256, 256, 0, stream>>>(tki, cursor, slot_tok, tok2slot);

  // 7) fc -> he [NPAIR][HID] bf16 w/ GELU (exact rowblock grid)
  {
    GArgs f = {};
    f.A = h; f.Bt = fc_wT; f.bias = fc_b;
    f.M = Nc; f.N = HIDc; f.K = Cc; f.lda = Cc; f.ldb = Cc; f.klen = Cc;
    f.Bstride = (size_t)HIDc * Cc; f.biasStride = HIDc;
    f.eoff = eoff; f.slot_tok = slot_tok;
    f.tbl_e = tbl_e; f.tbl_r0 = tbl_r0; f.tbl_n = tbl_n;
    f.outB = he;
    gemm128b<2><<<dim3(HIDc / 128, NRBMAX, 1), 256, 0, stream>>>(f);
  }

  // 8) pj (single K pass) -> pairout [NPAIR][C] bf16 (bias incl.)
  {
    GArgs pj = {};
    pj.A = he; pj.Bt = pj_wT; pj.bias = pj_b;
    pj.M = Nc; pj.N = Cc; pj.K = HIDc; pj.lda = HIDc; pj.ldb = HIDc; pj.klen = HIDc;
    pj.Bstride = (size_t)Cc * HIDc; pj.biasStride = Cc;
    pj.eoff = eoff;
    pj.tbl_e = tbl_e; pj.tbl_r0 = tbl_r0; pj.tbl_n = tbl_n;
    pj.outB = pairout;
    gemm128b<3><<<dim3(Cc / 128, NRBMAX, 1), 256, 0, stream>>>(pj);
  }

  // 9) deterministic combine into d_out
  combine_kernel<<<Nc, 256, 0, stream>>>(pairout, tkp, tok2slot, out);
}

// Round 16
// 549.242 us; speedup vs baseline: 1.1758x; 1.1213x over previous
//
#include <hip/hip_runtime.h>
#include <math.h>

// ---------------------------------------------------------------------------
// Fused transformer block w/ MoE (B=2,T=2048,C=1024,H=16,D=64,E=8,topK=2)
// Round 16: r15 kernels (616us best) + launch consolidation: routing
// (memset+count+scan+assign) -> 1 single-block kernel; 4 convT -> 1 launch.
// ---------------------------------------------------------------------------

typedef __bf16 b16v8 __attribute__((ext_vector_type(8)));
typedef float f32x4 __attribute__((ext_vector_type(4)));

#define MFMA(a, b, c) __builtin_amdgcn_mfma_f32_16x16x32_bf16(a, b, c, 0, 0, 0)

#define GLOAD_LDS16(g, l)                                          \
  __builtin_amdgcn_global_load_lds(                                \
      (const __attribute__((address_space(1))) void*)(g),          \
      (__attribute__((address_space(3))) void*)(l), 16, 0, 0)

constexpr int Bc = 2, Tc = 2048, Cc = 1024, Hc = 16, Dc = 64;
constexpr int Nc = Bc * Tc;       // 4096 tokens
constexpr int HIDc = 4096;        // 4*C
constexpr int Ec = 8;
constexpr int NPAIR = Nc * 2;     // 8192
constexpr int NRBMAX = NPAIR / 128 + Ec;  // 72
constexpr float LOG2E = 1.4426950408889634f;

__device__ inline unsigned short f32_bf16(float f) {
  union { float f; unsigned u; } x; x.f = f;
  unsigned r = x.u + 0x7fffu + ((x.u >> 16) & 1u);   // RNE
  return (unsigned short)(r >> 16);
}

__device__ inline float bf16_f32(unsigned short u) {
  union { unsigned u; float f; } x; x.u = ((unsigned)u) << 16;
  return x.f;
}

// gelu(x) = x * sigmoid(1.595769122*(x+0.044715x^3)); exp2-domain
__device__ inline float gelu_f(float x) {
  float t = 2.3021188f * x * (1.f + 0.044715f * x * x);
  float e = __builtin_amdgcn_exp2f(-t);
  return x * __builtin_amdgcn_rcpf(1.f + e);
}

// LDS element index for [row][64-elem] rows with 16B-granule XOR swizzle.
__device__ inline int swz(int row, int g) {
  return row * 64 + ((g ^ (row & 7)) * 8);
}

// ---------------------------------------------------------------------------
// Fused transpose+convert for all 4 weight tensors in ONE launch.
// Per-job: src f32 [batch][K][N] -> dst bf16 [batch][N][K], 64x64 tiles.
// ---------------------------------------------------------------------------
struct ConvJobs {
  const float* src[4];
  unsigned short* dst[4];
  int K[4], N[4];
  int start[4];   // flat tile-block start per job (ascending)
};

__global__ __launch_bounds__(256) void convT_all(ConvJobs j) {
  const int id = blockIdx.x;
  int which = 0;
#pragma unroll
  for (int q = 1; q < 4; ++q) which = (id >= j.start[q]) ? q : which;
  const int local = id - j.start[which];
  const int K = j.K[which], N = j.N[which];
  const int ntx = N >> 6, nty = K >> 6;
  const int perb = ntx * nty;
  const int batch = local / perb;
  const int rem = local - batch * perb;
  const int n0 = (rem % ntx) * 64, k0 = (rem / ntx) * 64;
  const float* src = j.src[which] + (size_t)batch * K * N;
  unsigned short* dst = j.dst[which] + (size_t)batch * K * N;

  __shared__ float t[64][65];
  const int tid = threadIdx.x;
#pragma unroll
  for (int jj = 0; jj < 4; ++jj) {
    int idx = jj * 256 + tid;
    int r = idx >> 4;
    int c4 = (idx & 15) << 2;
    float4 v = *(const float4*)&src[(size_t)(k0 + r) * N + n0 + c4];
    t[r][c4] = v.x; t[r][c4 + 1] = v.y; t[r][c4 + 2] = v.z; t[r][c4 + 3] = v.w;
  }
  __syncthreads();
#pragma unroll
  for (int jj = 0; jj < 4; ++jj) {
    int idx = jj * 256 + tid;
    int n = idx >> 4;
    int k4 = (idx & 15) << 2;
    ushort4 o;
    o.x = f32_bf16(t[k4][n]);
    o.y = f32_bf16(t[k4 + 1][n]);
    o.z = f32_bf16(t[k4 + 2][n]);
    o.w = f32_bf16(t[k4 + 3][n]);
    *(ushort4*)&dst[(size_t)(n0 + n) * K + k0 + k4] = o;
  }
}

// ---------------------------------------------------------------------------
// LayerNorm (f32 in -> bf16 out).
// ---------------------------------------------------------------------------
__global__ __launch_bounds__(256) void ln1_kernel(
    const float* __restrict__ x, const float* __restrict__ g,
    const float* __restrict__ b, unsigned short* __restrict__ out) {
  const int row = blockIdx.x;
  const int tid = threadIdx.x;
  const float* xr = x + (size_t)row * Cc;
  float v[4]; float s = 0.f, q = 0.f;
#pragma unroll
  for (int j = 0; j < 4; ++j) { v[j] = xr[tid + j * 256]; s += v[j]; q += v[j] * v[j]; }
#pragma unroll
  for (int m = 1; m <= 32; m <<= 1) { s += __shfl_xor(s, m); q += __shfl_xor(q, m); }
  __shared__ float red[2][4];
  const int w = tid >> 6;
  if ((tid & 63) == 0) { red[0][w] = s; red[1][w] = q; }
  __syncthreads();
  s = red[0][0] + red[0][1] + red[0][2] + red[0][3];
  q = red[1][0] + red[1][1] + red[1][2] + red[1][3];
  const float mean = s * (1.f / Cc);
  const float var = q * (1.f / Cc) - mean * mean;
  const float rstd = rsqrtf(var + 1e-5f);
#pragma unroll
  for (int j = 0; j < 4; ++j) {
    int c = tid + j * 256;
    out[(size_t)row * Cc + c] = f32_bf16((v[j] - mean) * rstd * g[c] + b[c]);
  }
}

// ---------------------------------------------------------------------------
// LN2 + router (f32 router math).
// ---------------------------------------------------------------------------
__global__ __launch_bounds__(256) void ln2_router_kernel(
    const float* __restrict__ x, const float* __restrict__ g,
    const float* __restrict__ b, const float* __restrict__ rw,
    unsigned short* __restrict__ out, int* __restrict__ tki, float* __restrict__ tkp) {
  const int row = blockIdx.x;
  const int tid = threadIdx.x;
  const float* xr = x + (size_t)row * Cc;
  float v[4]; float s = 0.f, q = 0.f;
#pragma unroll
  for (int j = 0; j < 4; ++j) { v[j] = xr[tid + j * 256]; s += v[j]; q += v[j] * v[j]; }
#pragma unroll
  for (int m = 1; m <= 32; m <<= 1) { s += __shfl_xor(s, m); q += __shfl_xor(q, m); }
  __shared__ float red[2][4];
  const int w = tid >> 6;
  if ((tid & 63) == 0) { red[0][w] = s; red[1][w] = q; }
  __syncthreads();
  s = red[0][0] + red[0][1] + red[0][2] + red[0][3];
  q = red[1][0] + red[1][1] + red[1][2] + red[1][3];
  const float mean = s * (1.f / Cc);
  const float var = q * (1.f / Cc) - mean * mean;
  const float rstd = rsqrtf(var + 1e-5f);
  float lg[8] = {0.f, 0.f, 0.f, 0.f, 0.f, 0.f, 0.f, 0.f};
#pragma unroll
  for (int j = 0; j < 4; ++j) {
    int c = tid + j * 256;
    float nv = (v[j] - mean) * rstd * g[c] + b[c];
    out[(size_t)row * Cc + c] = f32_bf16(nv);
    const float* rwc = rw + c * 8;
#pragma unroll
    for (int e = 0; e < 8; ++e) lg[e] += nv * rwc[e];
  }
#pragma unroll
  for (int m = 1; m <= 32; m <<= 1) {
#pragma unroll
    for (int e = 0; e < 8; ++e) lg[e] += __shfl_xor(lg[e], m);
  }
  __shared__ float rl[4][8];
  if ((tid & 63) == 0) {
#pragma unroll
    for (int e = 0; e < 8; ++e) rl[w][e] = lg[e];
  }
  __syncthreads();
  if (tid == 0) {
    float L[8];
#pragma unroll
    for (int e = 0; e < 8; ++e) L[e] = rl[0][e] + rl[1][e] + rl[2][e] + rl[3][e];
    int i1 = 0;
    for (int e = 1; e < 8; ++e) if (L[e] > L[i1]) i1 = e;
    int i2 = (i1 == 0) ? 1 : 0;
    for (int e = 0; e < 8; ++e) if (e != i1 && L[e] > L[i2]) i2 = e;
    float e2 = expf(L[i2] - L[i1]);
    float inv = 1.f / (1.f + e2);
    tki[row * 2] = i1; tki[row * 2 + 1] = i2;
    tkp[row * 2] = inv; tkp[row * 2 + 1] = e2 * inv;
  }
}

// ---------------------------------------------------------------------------
// Fused routing: histogram + offsets + rowblock table + slot assignment,
// ONE single-block launch (LDS cursors; slot order is atomic-order dependent
// but per-token arithmetic is order-independent -> deterministic output).
// ---------------------------------------------------------------------------
__global__ __launch_bounds__(256) void route_kernel(
    const int* __restrict__ tki,
    int* __restrict__ eoff, int* __restrict__ slot_tok,
    int* __restrict__ tok2slot, int* __restrict__ tbl_e,
    int* __restrict__ tbl_r0, int* __restrict__ tbl_n) {
  __shared__ int cnt[8];
  const int tid = threadIdx.x;
  if (tid < 8) cnt[tid] = 0;
  __syncthreads();
  for (int n = tid; n < Nc; n += 256) {
    atomicAdd(&cnt[tki[n * 2]], 1);
    atomicAdd(&cnt[tki[n * 2 + 1]], 1);
  }
  __syncthreads();
  if (tid == 0) {
    int s = 0, nb = 0;
    int base[8];
    for (int e = 0; e < Ec; ++e) {
      base[e] = s; eoff[e] = s;
      for (int r = 0; r < cnt[e]; r += 128) {
        tbl_e[nb] = e; tbl_r0[nb] = r; ++nb;
      }
      s += cnt[e];
    }
    eoff[Ec] = s;
    *tbl_n = nb;
    for (int e = 0; e < Ec; ++e) cnt[e] = base[e];   // reuse as cursors
  }
  __syncthreads();
  for (int n = tid; n < Nc; n += 256) {
#pragma unroll
    for (int kk = 0; kk < 2; ++kk) {
      int e = tki[n * 2 + kk];
      int slot = atomicAdd(&cnt[e], 1);
      slot_tok[slot] = n;
      tok2slot[n * 2 + kk] = slot;
    }
  }
}

// ---------------------------------------------------------------------------
struct GArgs {
  const unsigned short* A;    // bf16 [M][lda]
  const unsigned short* Bt;   // bf16 [N][ldb] (+ e*Bstride)
  const float* bias;          // f32 [N]      (+ e*biasStride)
  int M, N, K, lda, ldb, klen;
  size_t Bstride; int biasStride;
  const int* eoff;            // [E+1] (MODE 2/3)
  const int* slot_tok;        // (MODE 2)
  const int* tbl_e;           // rowblock table (MODE 2/3)
  const int* tbl_r0;
  const int* tbl_n;
  float* outF;                // MODE 1: out
  const float* resid;         // MODE 1
  unsigned short* outB;       // MODE 2: he ; MODE 3: pairout(bf16); MODE 0: q
  unsigned short* outK;       // MODE 0: k
  unsigned short* outV;       // MODE 0: v^T [B,H,D,T]
};

// ---------------------------------------------------------------------------
// 128x128 tile, BK=64, 4 waves (2x2), SINGLE buffer, XOR granule swizzle.
// 32 KiB LDS -> ~5 blocks/CU (r8 structure, session best).
// MODE: 0=QKV scatter, 1=proj+resid, 2=fc gather+gelu, 3=pj -> pairout(bf16)
// ---------------------------------------------------------------------------
template <int MODE>
__global__ __launch_bounds__(256) void gemm128b(GArgs g) {
  int e = 0, s0 = 0, Meff = g.M, row0;
  if constexpr (MODE == 2 || MODE == 3) {
    if ((int)blockIdx.y >= *g.tbl_n) return;
    e = g.tbl_e[blockIdx.y];
    row0 = g.tbl_r0[blockIdx.y];
    s0 = g.eoff[e];
    Meff = g.eoff[e + 1] - s0;
  } else {
    row0 = blockIdx.y * 128;
  }
  const int col0 = blockIdx.x * 128;

  __shared__ __align__(16) unsigned short As[128 * 64];
  __shared__ __align__(16) unsigned short Bs[128 * 64];

  const int tid = threadIdx.x;
  const int lane = tid & 63, w = tid >> 6;
  const int wr = w >> 1, wc = w & 1;
  const int fr = lane & 15, fg = lane >> 4;

  const unsigned short* Bt = g.Bt + (size_t)e * g.Bstride;
  const float* bias = g.bias + (size_t)e * g.biasStride;

  // LDS dest linear (gload_lds); GLOBAL source granule pre-swizzled (#21).
  size_t aaddr[4], baddr[4];
#pragma unroll
  for (int i = 0; i < 4; ++i) {
    int pos = i * 256 + tid;
    int r = pos >> 3;
    int c8 = ((pos & 7) ^ (r & 7)) * 8;
    int gr = row0 + r;
    if (gr >= Meff) gr = Meff - 1;
    int srcrow;
    if constexpr (MODE == 2) srcrow = g.slot_tok[s0 + gr];
    else if constexpr (MODE == 3) srcrow = s0 + gr;
    else srcrow = gr;
    aaddr[i] = (size_t)srcrow * g.lda + c8;
    baddr[i] = (size_t)(col0 + r) * g.ldb + c8;
  }

  auto STAGE = [&](int k0) {
#pragma unroll
    for (int i = 0; i < 4; ++i) {
      GLOAD_LDS16(g.A + aaddr[i] + k0, &As[i * 2048 + w * 512]);
      GLOAD_LDS16(Bt + baddr[i] + k0, &Bs[i * 2048 + w * 512]);
    }
  };

  f32x4 acc[4][4] = {};
  const int nt = g.klen / 64;

  for (int t = 0; t < nt; ++t) {
    if (t) __syncthreads();
    STAGE(t * 64);
    __syncthreads();
    b16v8 af[4][2], bf_[4][2];
#pragma unroll
    for (int mi = 0; mi < 4; ++mi) {
      const int ar = wr * 64 + mi * 16 + fr;
      af[mi][0] = *(const b16v8*)&As[swz(ar, fg)];
      af[mi][1] = *(const b16v8*)&As[swz(ar, 4 + fg)];
    }
#pragma unroll
    for (int ni = 0; ni < 4; ++ni) {
      const int br = wc * 64 + ni * 16 + fr;
      bf_[ni][0] = *(const b16v8*)&Bs[swz(br, fg)];
      bf_[ni][1] = *(const b16v8*)&Bs[swz(br, 4 + fg)];
    }
#pragma unroll
    for (int mi = 0; mi < 4; ++mi)
#pragma unroll
      for (int ni = 0; ni < 4; ++ni) {
        acc[mi][ni] = MFMA(af[mi][0], bf_[ni][0], acc[mi][ni]);
        acc[mi][ni] = MFMA(af[mi][1], bf_[ni][1], acc[mi][ni]);
      }
  }

#pragma unroll
  for (int mi = 0; mi < 4; ++mi) {
#pragma unroll
    for (int ni = 0; ni < 4; ++ni) {
#pragma unroll
      for (int rr = 0; rr < 4; ++rr) {
        int row = row0 + wr * 64 + mi * 16 + fg * 4 + rr;
        int col = col0 + wc * 64 + ni * 16 + fr;
        if (row >= Meff) continue;
        float val = acc[mi][ni][rr] + bias[col];
        if constexpr (MODE == 0) {
          int bb = row >> 11, tt = row & (Tc - 1);
          int which = col >> 10, cj = col & (Cc - 1);
          int hd = cj >> 6, d = cj & 63;
          if (which == 0)
            g.outB[(((size_t)(bb * Hc + hd)) * Tc + tt) * Dc + d] = f32_bf16(val);
          else if (which == 1)
            g.outK[(((size_t)(bb * Hc + hd)) * Tc + tt) * Dc + d] = f32_bf16(val);
          else
            g.outV[(((size_t)(bb * Hc + hd)) * Dc + d) * Tc + tt] = f32_bf16(val);
        } else if constexpr (MODE == 1) {
          size_t o = (size_t)row * g.N + col;
          g.outF[o] = val + g.resid[o];
        } else if constexpr (MODE == 2) {
          g.outB[(size_t)(s0 + row) * g.N + col] = f32_bf16(gelu_f(val));
        } else {
          g.outB[(size_t)(s0 + row) * g.N + col] = f32_bf16(val);
        }
      }
    }
  }
}

// ---------------------------------------------------------------------------
// Flash-style causal attention. 8 waves, 128 q-rows, KV tile 64.
// Heavy-first dispatch; T14 reg-prefetch; exact no-growth fast path.
// ---------------------------------------------------------------------------
__global__ __launch_bounds__(512) void attn_kernel(
    const unsigned short* __restrict__ q, const unsigned short* __restrict__ k,
    const unsigned short* __restrict__ v, unsigned short* __restrict__ y) {
  const int qt = gridDim.x - 1 - blockIdx.x;   // heavy-first
  const int bh = blockIdx.y;
  const int qbase = qt * 128;
  __shared__ __align__(16) unsigned short ldsK[64][72];
  __shared__ __align__(16) unsigned short ldsVT[64][72];     // [d][kv]
  __shared__ __align__(16) unsigned short ldsP[8][16][72];
  const int tid = threadIdx.x, lane = tid & 63, w = tid >> 6;
  const int fr = lane & 15, fg = lane >> 4;
  const size_t base = (size_t)bh * Tc * Dc;
  const int qrow = qbase + w * 16 + fr;
  b16v8 qa0 = *(const b16v8*)(q + base + (size_t)qrow * Dc + fg * 8);
  b16v8 qa1 = *(const b16v8*)(q + base + (size_t)qrow * Dc + 32 + fg * 8);
  float m[4], lsum[4] = {0.f, 0.f, 0.f, 0.f};
#pragma unroll
  for (int r = 0; r < 4; ++r) m[r] = -3.0e38f;
  f32x4 oacc[4] = {};
  constexpr float SC = 0.125f * LOG2E;

  const int sr = tid >> 3, scb = (tid & 7) * 8;
  const int ntile = (qbase + 128) / 64;

  *(uint4*)&ldsK[sr][scb]  = *(const uint4*)(k + base + (size_t)sr * Dc + scb);
  *(uint4*)&ldsVT[sr][scb] = *(const uint4*)(v + base + (size_t)sr * Tc + scb);
  __syncthreads();

  for (int ti = 0; ti < ntile; ++ti) {
    const int kb = ti * 64;
    uint4 kreg, vreg;
    const bool more = (ti + 1 < ntile);
    if (more) {
      const int kn = kb + 64;
      kreg = *(const uint4*)(k + base + (size_t)(kn + sr) * Dc + scb);
      vreg = *(const uint4*)(v + base + (size_t)sr * Tc + kn + scb);
    }

    f32x4 s[4];
#pragma unroll
    for (int ni = 0; ni < 4; ++ni) {
      b16v8 kb0 = *(const b16v8*)&ldsK[ni * 16 + fr][fg * 8];
      b16v8 kb1 = *(const b16v8*)&ldsK[ni * 16 + fr][32 + fg * 8];
      f32x4 z = {};
      z = MFMA(qa0, kb0, z);
      z = MFMA(qa1, kb1, z);
      s[ni] = z;
    }
    const bool diag = (kb + 64 > qbase + w * 16);
#pragma unroll
    for (int ni = 0; ni < 4; ++ni) {
#pragma unroll
      for (int r = 0; r < 4; ++r) {
        float sv = s[ni][r] * SC;
        if (diag) {
          int gq = qbase + w * 16 + fg * 4 + r;
          int kv = kb + ni * 16 + fr;
          if (kv > gq) sv = -3.0e38f;
        }
        s[ni][r] = sv;
      }
    }
    float mx[4];
    bool grow = false;
#pragma unroll
    for (int r = 0; r < 4; ++r) {
      float t = fmaxf(fmaxf(s[0][r], s[1][r]), fmaxf(s[2][r], s[3][r]));
#pragma unroll
      for (int msk = 1; msk <= 8; msk <<= 1) t = fmaxf(t, __shfl_xor(t, msk));
      mx[r] = t;
      grow = grow || (t > m[r]);
    }
    if (__any(grow)) {
#pragma unroll
      for (int r = 0; r < 4; ++r) {
        float mnew = fmaxf(m[r], mx[r]);
        float alpha = __builtin_amdgcn_exp2f(m[r] - mnew);
        float psum = 0.f;
#pragma unroll
        for (int ni = 0; ni < 4; ++ni) {
          float pp = __builtin_amdgcn_exp2f(s[ni][r] - mnew);
          s[ni][r] = pp;
          psum += pp;
        }
#pragma unroll
        for (int msk = 1; msk <= 8; msk <<= 1) psum += __shfl_xor(psum, msk);
        lsum[r] = lsum[r] * alpha + psum;
        m[r] = mnew;
#pragma unroll
        for (int ni = 0; ni < 4; ++ni) {
          oacc[ni][r] = oacc[ni][r] * alpha;
          ldsP[w][fg * 4 + r][ni * 16 + fr] = f32_bf16(s[ni][r]);
        }
      }
    } else {
#pragma unroll
      for (int r = 0; r < 4; ++r) {
        float psum = 0.f;
#pragma unroll
        for (int ni = 0; ni < 4; ++ni) {
          float pp = __builtin_amdgcn_exp2f(s[ni][r] - m[r]);
          s[ni][r] = pp;
          psum += pp;
        }
#pragma unroll
        for (int msk = 1; msk <= 8; msk <<= 1) psum += __shfl_xor(psum, msk);
        lsum[r] += psum;
#pragma unroll
        for (int ni = 0; ni < 4; ++ni)
          ldsP[w][fg * 4 + r][ni * 16 + fr] = f32_bf16(s[ni][r]);
      }
    }
    asm volatile("s_waitcnt lgkmcnt(0)" ::: "memory");
    __builtin_amdgcn_sched_barrier(0);
    b16v8 pa0 = *(const b16v8*)&ldsP[w][fr][fg * 8];
    b16v8 pa1 = *(const b16v8*)&ldsP[w][fr][32 + fg * 8];
#pragma unroll
    for (int ni = 0; ni < 4; ++ni) {
      b16v8 vb0 = *(const b16v8*)&ldsVT[ni * 16 + fr][fg * 8];
      b16v8 vb1 = *(const b16v8*)&ldsVT[ni * 16 + fr][32 + fg * 8];
      oacc[ni] = MFMA(pa0, vb0, oacc[ni]);
      oacc[ni] = MFMA(pa1, vb1, oacc[ni]);
    }

    if (more) {
      __syncthreads();
      *(uint4*)&ldsK[sr][scb]  = kreg;
      *(uint4*)&ldsVT[sr][scb] = vreg;
      __syncthreads();
    }
  }

  const int bb = bh >> 4, hh = bh & 15;
#pragma unroll
  for (int r = 0; r < 4; ++r) {
    float rl = __builtin_amdgcn_rcpf(lsum[r]);
#pragma unroll
    for (int ni = 0; ni < 4; ++ni) {
      int t = qbase + w * 16 + fg * 4 + r;
      int d = ni * 16 + fr;
      y[((size_t)(bb * Tc + t)) * Cc + hh * Dc + d] = f32_bf16(oacc[ni][r] * rl);
    }
  }
}

// ---------------------------------------------------------------------------
// Deterministic combine (bf16 pairout): out[n] += p0*pair[s0] + p1*pair[s1]
// ---------------------------------------------------------------------------
__global__ __launch_bounds__(256) void combine_kernel(
    const unsigned short* __restrict__ pair, const float* __restrict__ tkp,
    const int* __restrict__ tok2slot, float* __restrict__ out) {
  const int n = blockIdx.x;
  const int c4 = threadIdx.x * 4;
  const int s0 = tok2slot[n * 2], s1 = tok2slot[n * 2 + 1];
  const float p0 = tkp[n * 2], p1 = tkp[n * 2 + 1];
  ushort4 a = *(const ushort4*)&pair[(size_t)s0 * Cc + c4];
  ushort4 b = *(const ushort4*)&pair[(size_t)s1 * Cc + c4];
  float4 o = *(float4*)&out[(size_t)n * Cc + c4];
  o.x += p0 * bf16_f32(a.x) + p1 * bf16_f32(b.x);
  o.y += p0 * bf16_f32(a.y) + p1 * bf16_f32(b.y);
  o.z += p0 * bf16_f32(a.z) + p1 * bf16_f32(b.z);
  o.w += p0 * bf16_f32(a.w) + p1 * bf16_f32(b.w);
  *(float4*)&out[(size_t)n * Cc + c4] = o;
}

// ---------------------------------------------------------------------------
extern "C" void kernel_launch(void* const* d_in, const int* in_sizes, int n_in,
                              void* d_out, int out_size, void* d_ws, size_t ws_size,
                              hipStream_t stream) {
  const float* x        = (const float*)d_in[0];
  const float* ln1_g    = (const float*)d_in[1];
  const float* ln1_b    = (const float*)d_in[2];
  const float* ln2_g    = (const float*)d_in[3];
  const float* ln2_b    = (const float*)d_in[4];
  const float* attn_w   = (const float*)d_in[5];
  const float* attn_b   = (const float*)d_in[6];
  const float* proj_w   = (const float*)d_in[7];
  const float* proj_b   = (const float*)d_in[8];
  const float* router_w = (const float*)d_in[9];
  const float* fc_w     = (const float*)d_in[10];
  const float* fc_b     = (const float*)d_in[11];
  const float* pj_w     = (const float*)d_in[12];
  const float* pj_b     = (const float*)d_in[13];
  float* out = (float*)d_out;

  char* ws = (char*)d_ws;
  size_t off = 0;
  auto alloc = [&](size_t bytes) -> void* {
    void* p = ws + off;
    off = (off + bytes + 255) & ~(size_t)255;
    return p;
  };
  unsigned short* attn_wT = (unsigned short*)alloc((size_t)3 * Cc * Cc * 2);
  unsigned short* proj_wT = (unsigned short*)alloc((size_t)Cc * Cc * 2);
  unsigned short* fc_wT   = (unsigned short*)alloc((size_t)Ec * HIDc * Cc * 2);
  unsigned short* pj_wT   = (unsigned short*)alloc((size_t)Ec * Cc * HIDc * 2);
  unsigned short* h    = (unsigned short*)alloc((size_t)Nc * Cc * 2);
  unsigned short* qb   = (unsigned short*)alloc((size_t)Nc * Cc * 2);   // [B,H,T,D]
  unsigned short* kbuf = (unsigned short*)alloc((size_t)Nc * Cc * 2);   // [B,H,T,D]
  unsigned short* vbuf = (unsigned short*)alloc((size_t)Nc * Cc * 2);   // [B,H,D,T]
  unsigned short* ybuf = (unsigned short*)alloc((size_t)Nc * Cc * 2);   // [N,C]
  unsigned short* he   = (unsigned short*)alloc((size_t)NPAIR * HIDc * 2);
  unsigned short* pairout = (unsigned short*)alloc((size_t)NPAIR * Cc * 2);
  int*   tki     = (int*)alloc((size_t)Nc * 2 * 4);
  float* tkp     = (float*)alloc((size_t)Nc * 2 * 4);
  int*   eoff    = (int*)alloc((Ec + 1) * 4);
  int*   slot_tok= (int*)alloc((size_t)NPAIR * 4);
  int*   tok2slot= (int*)alloc((size_t)Nc * 2 * 4);
  int*   tbl_e   = (int*)alloc(NRBMAX * 4);
  int*   tbl_r0  = (int*)alloc(NRBMAX * 4);
  int*   tbl_n   = (int*)alloc(4);
  (void)ws_size; (void)in_sizes; (void)n_in; (void)out_size;

  // 0) weight pre-transpose/convert: all 4 tensors, ONE launch
  {
    ConvJobs cj;
    cj.src[0] = attn_w;  cj.dst[0] = attn_wT; cj.K[0] = Cc;   cj.N[0] = 3 * Cc;
    cj.src[1] = proj_w;  cj.dst[1] = proj_wT; cj.K[1] = Cc;   cj.N[1] = Cc;
    cj.src[2] = fc_w;    cj.dst[2] = fc_wT;   cj.K[2] = Cc;   cj.N[2] = HIDc;
    cj.src[3] = pj_w;    cj.dst[3] = pj_wT;   cj.K[3] = HIDc; cj.N[3] = Cc;
    const int t0 = (3 * Cc / 64) * (Cc / 64);          // 768
    const int t1 = (Cc / 64) * (Cc / 64);              // 256
    const int t2 = (HIDc / 64) * (Cc / 64) * Ec;       // 8192
    const int t3 = (Cc / 64) * (HIDc / 64) * Ec;       // 8192
    cj.start[0] = 0;
    cj.start[1] = t0;
    cj.start[2] = t0 + t1;
    cj.start[3] = t0 + t1 + t2;
    convT_all<<<t0 + t1 + t2 + t3, 256, 0, stream>>>(cj);
  }

  // 1) LN1
  ln1_kernel<<<Nc, 256, 0, stream>>>(x, ln1_g, ln1_b, h);

  // 2) QKV GEMM -> q/k [B,H,T,D], v^T [B,H,D,T]
  {
    GArgs a = {};
    a.A = h; a.Bt = attn_wT; a.bias = attn_b;
    a.M = Nc; a.N = 3 * Cc; a.K = Cc; a.lda = Cc; a.ldb = Cc; a.klen = Cc;
    a.outB = qb; a.outK = kbuf; a.outV = vbuf;
    gemm128b<0><<<dim3(3 * Cc / 128, Nc / 128, 1), 256, 0, stream>>>(a);
  }

  // 3) causal attention -> y [N,C] bf16 (heavy-first)
  attn_kernel<<<dim3(Tc / 128, Bc * Hc), 512, 0, stream>>>(qb, kbuf, vbuf, ybuf);

  // 4) proj + residual -> d_out (f32)
  {
    GArgs p = {};
    p.A = ybuf; p.Bt = proj_wT; p.bias = proj_b;
    p.M = Nc; p.N = Cc; p.K = Cc; p.lda = Cc; p.ldb = Cc; p.klen = Cc;
    p.outF = out; p.resid = x;
    gemm128b<1><<<dim3(Cc / 128, Nc / 128, 1), 256, 0, stream>>>(p);
  }

  // 5) LN2 + router -> h (bf16), top-2
  ln2_router_kernel<<<Nc, 256, 0, stream>>>(out, ln2_g, ln2_b, router_w, h, tki, tkp);

  // 6) routing: ONE single-block kernel (histogram+scan+table+assign)
  route_kernel<<<1, 256, 0, stream>>>(tki, eoff, slot_tok, tok2slot,
                                      tbl_e, tbl_r0, tbl_n);

  // 7) fc -> he [NPAIR][HID] bf16 w/ GELU (exact rowblock grid)
  {
    GArgs f = {};
    f.A = h; f.Bt = fc_wT; f.bias = fc_b;
    f.M = Nc; f.N = HIDc; f.K = Cc; f.lda = Cc; f.ldb = Cc; f.klen = Cc;
    f.Bstride = (size_t)HIDc * Cc; f.biasStride = HIDc;
    f.eoff = eoff; f.slot_tok = slot_tok;
    f.tbl_e = tbl_e; f.tbl_r0 = tbl_r0; f.tbl_n = tbl_n;
    f.outB = he;
    gemm128b<2><<<dim3(HIDc / 128, NRBMAX, 1), 256, 0, stream>>>(f);
  }

  // 8) pj (single K pass) -> pairout [NPAIR][C] bf16 (bias incl.)
  {
    GArgs pj = {};
    pj.A = he; pj.Bt = pj_wT; pj.bias = pj_b;
    pj.M = Nc; pj.N = Cc; pj.K = HIDc; pj.lda = HIDc; pj.ldb = HIDc; pj.klen = HIDc;
    pj.Bstride = (size_t)Cc * HIDc; pj.biasStride = Cc;
    pj.eoff = eoff;
    pj.tbl_e = tbl_e; pj.tbl_r0 = tbl_r0; pj.tbl_n = tbl_n;
    pj.outB = pairout;
    gemm128b<3><<<dim3(Cc / 128, NRBMAX, 1), 256, 0, stream>>>(pj);
  }

  // 9) deterministic combine into d_out
  combine_kernel<<<Nc, 256, 0, stream>>>(pairout, tkp, tok2slot, out);
}

// Round 17
// 546.839 us; speedup vs baseline: 1.1809x; 1.0044x over previous
//
#include <hip/hip_runtime.h>
#include <math.h>

// ---------------------------------------------------------------------------
// Fused transformer block w/ MoE (B=2,T=2048,C=1024,H=16,D=64,E=8,topK=2)
// Round 17: r16 (549us) + ln1 folded into the convT_all launch (independent
// work shares one launch; LN blocks backfill convT tail drain).
// ---------------------------------------------------------------------------

typedef __bf16 b16v8 __attribute__((ext_vector_type(8)));
typedef float f32x4 __attribute__((ext_vector_type(4)));

#define MFMA(a, b, c) __builtin_amdgcn_mfma_f32_16x16x32_bf16(a, b, c, 0, 0, 0)

#define GLOAD_LDS16(g, l)                                          \
  __builtin_amdgcn_global_load_lds(                                \
      (const __attribute__((address_space(1))) void*)(g),          \
      (__attribute__((address_space(3))) void*)(l), 16, 0, 0)

constexpr int Bc = 2, Tc = 2048, Cc = 1024, Hc = 16, Dc = 64;
constexpr int Nc = Bc * Tc;       // 4096 tokens
constexpr int HIDc = 4096;        // 4*C
constexpr int Ec = 8;
constexpr int NPAIR = Nc * 2;     // 8192
constexpr int NRBMAX = NPAIR / 128 + Ec;  // 72
constexpr float LOG2E = 1.4426950408889634f;

__device__ inline unsigned short f32_bf16(float f) {
  union { float f; unsigned u; } x; x.f = f;
  unsigned r = x.u + 0x7fffu + ((x.u >> 16) & 1u);   // RNE
  return (unsigned short)(r >> 16);
}

__device__ inline float bf16_f32(unsigned short u) {
  union { unsigned u; float f; } x; x.u = ((unsigned)u) << 16;
  return x.f;
}

// gelu(x) = x * sigmoid(1.595769122*(x+0.044715x^3)); exp2-domain
__device__ inline float gelu_f(float x) {
  float t = 2.3021188f * x * (1.f + 0.044715f * x * x);
  float e = __builtin_amdgcn_exp2f(-t);
  return x * __builtin_amdgcn_rcpf(1.f + e);
}

// LDS element index for [row][64-elem] rows with 16B-granule XOR swizzle.
__device__ inline int swz(int row, int g) {
  return row * 64 + ((g ^ (row & 7)) * 8);
}

// ---------------------------------------------------------------------------
// Fused prologue: 4 weight transpose+convert jobs AND ln1 in ONE launch.
// convT blocks: 64x64 tile f32 [K][N] -> bf16 [N][K].
// ln1 blocks (id >= lnStart): one token row each, LN(x) -> h bf16.
// ---------------------------------------------------------------------------
struct ProJobs {
  const float* src[4];
  unsigned short* dst[4];
  int K[4], N[4];
  int start[4];
  int lnStart;                 // first ln1 block
  const float* x;
  const float* ln_g;
  const float* ln_b;
  unsigned short* h;
};

__global__ __launch_bounds__(256) void prologue_all(ProJobs j) {
  const int id = blockIdx.x;
  const int tid = threadIdx.x;

  if (id >= j.lnStart) {
    // ---- ln1 body ----
    const int row = id - j.lnStart;
    const float* xr = j.x + (size_t)row * Cc;
    float v[4]; float s = 0.f, q = 0.f;
#pragma unroll
    for (int jj = 0; jj < 4; ++jj) {
      v[jj] = xr[tid + jj * 256]; s += v[jj]; q += v[jj] * v[jj];
    }
#pragma unroll
    for (int m = 1; m <= 32; m <<= 1) { s += __shfl_xor(s, m); q += __shfl_xor(q, m); }
    __shared__ float red[2][4];
    const int w = tid >> 6;
    if ((tid & 63) == 0) { red[0][w] = s; red[1][w] = q; }
    __syncthreads();
    s = red[0][0] + red[0][1] + red[0][2] + red[0][3];
    q = red[1][0] + red[1][1] + red[1][2] + red[1][3];
    const float mean = s * (1.f / Cc);
    const float var = q * (1.f / Cc) - mean * mean;
    const float rstd = rsqrtf(var + 1e-5f);
#pragma unroll
    for (int jj = 0; jj < 4; ++jj) {
      int c = tid + jj * 256;
      j.h[(size_t)row * Cc + c] = f32_bf16((v[jj] - mean) * rstd * j.ln_g[c] + j.ln_b[c]);
    }
    return;
  }

  // ---- convT body ----
  int which = 0;
#pragma unroll
  for (int q = 1; q < 4; ++q) which = (id >= j.start[q]) ? q : which;
  const int local = id - j.start[which];
  const int K = j.K[which], N = j.N[which];
  const int ntx = N >> 6, nty = K >> 6;
  const int perb = ntx * nty;
  const int batch = local / perb;
  const int rem = local - batch * perb;
  const int n0 = (rem % ntx) * 64, k0 = (rem / ntx) * 64;
  const float* src = j.src[which] + (size_t)batch * K * N;
  unsigned short* dst = j.dst[which] + (size_t)batch * K * N;

  __shared__ float t[64][65];
#pragma unroll
  for (int jj = 0; jj < 4; ++jj) {
    int idx = jj * 256 + tid;
    int r = idx >> 4;
    int c4 = (idx & 15) << 2;
    float4 v = *(const float4*)&src[(size_t)(k0 + r) * N + n0 + c4];
    t[r][c4] = v.x; t[r][c4 + 1] = v.y; t[r][c4 + 2] = v.z; t[r][c4 + 3] = v.w;
  }
  __syncthreads();
#pragma unroll
  for (int jj = 0; jj < 4; ++jj) {
    int idx = jj * 256 + tid;
    int n = idx >> 4;
    int k4 = (idx & 15) << 2;
    ushort4 o;
    o.x = f32_bf16(t[k4][n]);
    o.y = f32_bf16(t[k4 + 1][n]);
    o.z = f32_bf16(t[k4 + 2][n]);
    o.w = f32_bf16(t[k4 + 3][n]);
    *(ushort4*)&dst[(size_t)(n0 + n) * K + k0 + k4] = o;
  }
}

// ---------------------------------------------------------------------------
// LN2 + router (f32 router math).
// ---------------------------------------------------------------------------
__global__ __launch_bounds__(256) void ln2_router_kernel(
    const float* __restrict__ x, const float* __restrict__ g,
    const float* __restrict__ b, const float* __restrict__ rw,
    unsigned short* __restrict__ out, int* __restrict__ tki, float* __restrict__ tkp) {
  const int row = blockIdx.x;
  const int tid = threadIdx.x;
  const float* xr = x + (size_t)row * Cc;
  float v[4]; float s = 0.f, q = 0.f;
#pragma unroll
  for (int j = 0; j < 4; ++j) { v[j] = xr[tid + j * 256]; s += v[j]; q += v[j] * v[j]; }
#pragma unroll
  for (int m = 1; m <= 32; m <<= 1) { s += __shfl_xor(s, m); q += __shfl_xor(q, m); }
  __shared__ float red[2][4];
  const int w = tid >> 6;
  if ((tid & 63) == 0) { red[0][w] = s; red[1][w] = q; }
  __syncthreads();
  s = red[0][0] + red[0][1] + red[0][2] + red[0][3];
  q = red[1][0] + red[1][1] + red[1][2] + red[1][3];
  const float mean = s * (1.f / Cc);
  const float var = q * (1.f / Cc) - mean * mean;
  const float rstd = rsqrtf(var + 1e-5f);
  float lg[8] = {0.f, 0.f, 0.f, 0.f, 0.f, 0.f, 0.f, 0.f};
#pragma unroll
  for (int j = 0; j < 4; ++j) {
    int c = tid + j * 256;
    float nv = (v[j] - mean) * rstd * g[c] + b[c];
    out[(size_t)row * Cc + c] = f32_bf16(nv);
    const float* rwc = rw + c * 8;
#pragma unroll
    for (int e = 0; e < 8; ++e) lg[e] += nv * rwc[e];
  }
#pragma unroll
  for (int m = 1; m <= 32; m <<= 1) {
#pragma unroll
    for (int e = 0; e < 8; ++e) lg[e] += __shfl_xor(lg[e], m);
  }
  __shared__ float rl[4][8];
  if ((tid & 63) == 0) {
#pragma unroll
    for (int e = 0; e < 8; ++e) rl[w][e] = lg[e];
  }
  __syncthreads();
  if (tid == 0) {
    float L[8];
#pragma unroll
    for (int e = 0; e < 8; ++e) L[e] = rl[0][e] + rl[1][e] + rl[2][e] + rl[3][e];
    int i1 = 0;
    for (int e = 1; e < 8; ++e) if (L[e] > L[i1]) i1 = e;
    int i2 = (i1 == 0) ? 1 : 0;
    for (int e = 0; e < 8; ++e) if (e != i1 && L[e] > L[i2]) i2 = e;
    float e2 = expf(L[i2] - L[i1]);
    float inv = 1.f / (1.f + e2);
    tki[row * 2] = i1; tki[row * 2 + 1] = i2;
    tkp[row * 2] = inv; tkp[row * 2 + 1] = e2 * inv;
  }
}

// ---------------------------------------------------------------------------
// Fused routing: histogram + offsets + rowblock table + slot assignment.
// ---------------------------------------------------------------------------
__global__ __launch_bounds__(256) void route_kernel(
    const int* __restrict__ tki,
    int* __restrict__ eoff, int* __restrict__ slot_tok,
    int* __restrict__ tok2slot, int* __restrict__ tbl_e,
    int* __restrict__ tbl_r0, int* __restrict__ tbl_n) {
  __shared__ int cnt[8];
  const int tid = threadIdx.x;
  if (tid < 8) cnt[tid] = 0;
  __syncthreads();
  for (int n = tid; n < Nc; n += 256) {
    atomicAdd(&cnt[tki[n * 2]], 1);
    atomicAdd(&cnt[tki[n * 2 + 1]], 1);
  }
  __syncthreads();
  if (tid == 0) {
    int s = 0, nb = 0;
    int base[8];
    for (int e = 0; e < Ec; ++e) {
      base[e] = s; eoff[e] = s;
      for (int r = 0; r < cnt[e]; r += 128) {
        tbl_e[nb] = e; tbl_r0[nb] = r; ++nb;
      }
      s += cnt[e];
    }
    eoff[Ec] = s;
    *tbl_n = nb;
    for (int e = 0; e < Ec; ++e) cnt[e] = base[e];   // reuse as cursors
  }
  __syncthreads();
  for (int n = tid; n < Nc; n += 256) {
#pragma unroll
    for (int kk = 0; kk < 2; ++kk) {
      int e = tki[n * 2 + kk];
      int slot = atomicAdd(&cnt[e], 1);
      slot_tok[slot] = n;
      tok2slot[n * 2 + kk] = slot;
    }
  }
}

// ---------------------------------------------------------------------------
struct GArgs {
  const unsigned short* A;    // bf16 [M][lda]
  const unsigned short* Bt;   // bf16 [N][ldb] (+ e*Bstride)
  const float* bias;          // f32 [N]      (+ e*biasStride)
  int M, N, K, lda, ldb, klen;
  size_t Bstride; int biasStride;
  const int* eoff;            // [E+1] (MODE 2/3)
  const int* slot_tok;        // (MODE 2)
  const int* tbl_e;           // rowblock table (MODE 2/3)
  const int* tbl_r0;
  const int* tbl_n;
  float* outF;                // MODE 1: out
  const float* resid;         // MODE 1
  unsigned short* outB;       // MODE 2: he ; MODE 3: pairout(bf16); MODE 0: q
  unsigned short* outK;       // MODE 0: k
  unsigned short* outV;       // MODE 0: v^T [B,H,D,T]
};

// ---------------------------------------------------------------------------
// 128x128 tile, BK=64, 4 waves (2x2), SINGLE buffer, XOR granule swizzle.
// 32 KiB LDS -> ~5 blocks/CU (r8 structure, session best).
// MODE: 0=QKV scatter, 1=proj+resid, 2=fc gather+gelu, 3=pj -> pairout(bf16)
// ---------------------------------------------------------------------------
template <int MODE>
__global__ __launch_bounds__(256) void gemm128b(GArgs g) {
  int e = 0, s0 = 0, Meff = g.M, row0;
  if constexpr (MODE == 2 || MODE == 3) {
    if ((int)blockIdx.y >= *g.tbl_n) return;
    e = g.tbl_e[blockIdx.y];
    row0 = g.tbl_r0[blockIdx.y];
    s0 = g.eoff[e];
    Meff = g.eoff[e + 1] - s0;
  } else {
    row0 = blockIdx.y * 128;
  }
  const int col0 = blockIdx.x * 128;

  __shared__ __align__(16) unsigned short As[128 * 64];
  __shared__ __align__(16) unsigned short Bs[128 * 64];

  const int tid = threadIdx.x;
  const int lane = tid & 63, w = tid >> 6;
  const int wr = w >> 1, wc = w & 1;
  const int fr = lane & 15, fg = lane >> 4;

  const unsigned short* Bt = g.Bt + (size_t)e * g.Bstride;
  const float* bias = g.bias + (size_t)e * g.biasStride;

  // LDS dest linear (gload_lds); GLOBAL source granule pre-swizzled (#21).
  size_t aaddr[4], baddr[4];
#pragma unroll
  for (int i = 0; i < 4; ++i) {
    int pos = i * 256 + tid;
    int r = pos >> 3;
    int c8 = ((pos & 7) ^ (r & 7)) * 8;
    int gr = row0 + r;
    if (gr >= Meff) gr = Meff - 1;
    int srcrow;
    if constexpr (MODE == 2) srcrow = g.slot_tok[s0 + gr];
    else if constexpr (MODE == 3) srcrow = s0 + gr;
    else srcrow = gr;
    aaddr[i] = (size_t)srcrow * g.lda + c8;
    baddr[i] = (size_t)(col0 + r) * g.ldb + c8;
  }

  auto STAGE = [&](int k0) {
#pragma unroll
    for (int i = 0; i < 4; ++i) {
      GLOAD_LDS16(g.A + aaddr[i] + k0, &As[i * 2048 + w * 512]);
      GLOAD_LDS16(Bt + baddr[i] + k0, &Bs[i * 2048 + w * 512]);
    }
  };

  f32x4 acc[4][4] = {};
  const int nt = g.klen / 64;

  for (int t = 0; t < nt; ++t) {
    if (t) __syncthreads();
    STAGE(t * 64);
    __syncthreads();
    b16v8 af[4][2], bf_[4][2];
#pragma unroll
    for (int mi = 0; mi < 4; ++mi) {
      const int ar = wr * 64 + mi * 16 + fr;
      af[mi][0] = *(const b16v8*)&As[swz(ar, fg)];
      af[mi][1] = *(const b16v8*)&As[swz(ar, 4 + fg)];
    }
#pragma unroll
    for (int ni = 0; ni < 4; ++ni) {
      const int br = wc * 64 + ni * 16 + fr;
      bf_[ni][0] = *(const b16v8*)&Bs[swz(br, fg)];
      bf_[ni][1] = *(const b16v8*)&Bs[swz(br, 4 + fg)];
    }
#pragma unroll
    for (int mi = 0; mi < 4; ++mi)
#pragma unroll
      for (int ni = 0; ni < 4; ++ni) {
        acc[mi][ni] = MFMA(af[mi][0], bf_[ni][0], acc[mi][ni]);
        acc[mi][ni] = MFMA(af[mi][1], bf_[ni][1], acc[mi][ni]);
      }
  }

#pragma unroll
  for (int mi = 0; mi < 4; ++mi) {
#pragma unroll
    for (int ni = 0; ni < 4; ++ni) {
#pragma unroll
      for (int rr = 0; rr < 4; ++rr) {
        int row = row0 + wr * 64 + mi * 16 + fg * 4 + rr;
        int col = col0 + wc * 64 + ni * 16 + fr;
        if (row >= Meff) continue;
        float val = acc[mi][ni][rr] + bias[col];
        if constexpr (MODE == 0) {
          int bb = row >> 11, tt = row & (Tc - 1);
          int which = col >> 10, cj = col & (Cc - 1);
          int hd = cj >> 6, d = cj & 63;
          if (which == 0)
            g.outB[(((size_t)(bb * Hc + hd)) * Tc + tt) * Dc + d] = f32_bf16(val);
          else if (which == 1)
            g.outK[(((size_t)(bb * Hc + hd)) * Tc + tt) * Dc + d] = f32_bf16(val);
          else
            g.outV[(((size_t)(bb * Hc + hd)) * Dc + d) * Tc + tt] = f32_bf16(val);
        } else if constexpr (MODE == 1) {
          size_t o = (size_t)row * g.N + col;
          g.outF[o] = val + g.resid[o];
        } else if constexpr (MODE == 2) {
          g.outB[(size_t)(s0 + row) * g.N + col] = f32_bf16(gelu_f(val));
        } else {
          g.outB[(size_t)(s0 + row) * g.N + col] = f32_bf16(val);
        }
      }
    }
  }
}

// ---------------------------------------------------------------------------
// Flash-style causal attention. 8 waves, 128 q-rows, KV tile 64.
// Heavy-first dispatch; T14 reg-prefetch; exact no-growth fast path.
// ---------------------------------------------------------------------------
__global__ __launch_bounds__(512) void attn_kernel(
    const unsigned short* __restrict__ q, const unsigned short* __restrict__ k,
    const unsigned short* __restrict__ v, unsigned short* __restrict__ y) {
  const int qt = gridDim.x - 1 - blockIdx.x;   // heavy-first
  const int bh = blockIdx.y;
  const int qbase = qt * 128;
  __shared__ __align__(16) unsigned short ldsK[64][72];
  __shared__ __align__(16) unsigned short ldsVT[64][72];     // [d][kv]
  __shared__ __align__(16) unsigned short ldsP[8][16][72];
  const int tid = threadIdx.x, lane = tid & 63, w = tid >> 6;
  const int fr = lane & 15, fg = lane >> 4;
  const size_t base = (size_t)bh * Tc * Dc;
  const int qrow = qbase + w * 16 + fr;
  b16v8 qa0 = *(const b16v8*)(q + base + (size_t)qrow * Dc + fg * 8);
  b16v8 qa1 = *(const b16v8*)(q + base + (size_t)qrow * Dc + 32 + fg * 8);
  float m[4], lsum[4] = {0.f, 0.f, 0.f, 0.f};
#pragma unroll
  for (int r = 0; r < 4; ++r) m[r] = -3.0e38f;
  f32x4 oacc[4] = {};
  constexpr float SC = 0.125f * LOG2E;

  const int sr = tid >> 3, scb = (tid & 7) * 8;
  const int ntile = (qbase + 128) / 64;

  *(uint4*)&ldsK[sr][scb]  = *(const uint4*)(k + base + (size_t)sr * Dc + scb);
  *(uint4*)&ldsVT[sr][scb] = *(const uint4*)(v + base + (size_t)sr * Tc + scb);
  __syncthreads();

  for (int ti = 0; ti < ntile; ++ti) {
    const int kb = ti * 64;
    uint4 kreg, vreg;
    const bool more = (ti + 1 < ntile);
    if (more) {
      const int kn = kb + 64;
      kreg = *(const uint4*)(k + base + (size_t)(kn + sr) * Dc + scb);
      vreg = *(const uint4*)(v + base + (size_t)sr * Tc + kn + scb);
    }

    f32x4 s[4];
#pragma unroll
    for (int ni = 0; ni < 4; ++ni) {
      b16v8 kb0 = *(const b16v8*)&ldsK[ni * 16 + fr][fg * 8];
      b16v8 kb1 = *(const b16v8*)&ldsK[ni * 16 + fr][32 + fg * 8];
      f32x4 z = {};
      z = MFMA(qa0, kb0, z);
      z = MFMA(qa1, kb1, z);
      s[ni] = z;
    }
    const bool diag = (kb + 64 > qbase + w * 16);
#pragma unroll
    for (int ni = 0; ni < 4; ++ni) {
#pragma unroll
      for (int r = 0; r < 4; ++r) {
        float sv = s[ni][r] * SC;
        if (diag) {
          int gq = qbase + w * 16 + fg * 4 + r;
          int kv = kb + ni * 16 + fr;
          if (kv > gq) sv = -3.0e38f;
        }
        s[ni][r] = sv;
      }
    }
    float mx[4];
    bool grow = false;
#pragma unroll
    for (int r = 0; r < 4; ++r) {
      float t = fmaxf(fmaxf(s[0][r], s[1][r]), fmaxf(s[2][r], s[3][r]));
#pragma unroll
      for (int msk = 1; msk <= 8; msk <<= 1) t = fmaxf(t, __shfl_xor(t, msk));
      mx[r] = t;
      grow = grow || (t > m[r]);
    }
    if (__any(grow)) {
#pragma unroll
      for (int r = 0; r < 4; ++r) {
        float mnew = fmaxf(m[r], mx[r]);
        float alpha = __builtin_amdgcn_exp2f(m[r] - mnew);
        float psum = 0.f;
#pragma unroll
        for (int ni = 0; ni < 4; ++ni) {
          float pp = __builtin_amdgcn_exp2f(s[ni][r] - mnew);
          s[ni][r] = pp;
          psum += pp;
        }
#pragma unroll
        for (int msk = 1; msk <= 8; msk <<= 1) psum += __shfl_xor(psum, msk);
        lsum[r] = lsum[r] * alpha + psum;
        m[r] = mnew;
#pragma unroll
        for (int ni = 0; ni < 4; ++ni) {
          oacc[ni][r] = oacc[ni][r] * alpha;
          ldsP[w][fg * 4 + r][ni * 16 + fr] = f32_bf16(s[ni][r]);
        }
      }
    } else {
#pragma unroll
      for (int r = 0; r < 4; ++r) {
        float psum = 0.f;
#pragma unroll
        for (int ni = 0; ni < 4; ++ni) {
          float pp = __builtin_amdgcn_exp2f(s[ni][r] - m[r]);
          s[ni][r] = pp;
          psum += pp;
        }
#pragma unroll
        for (int msk = 1; msk <= 8; msk <<= 1) psum += __shfl_xor(psum, msk);
        lsum[r] += psum;
#pragma unroll
        for (int ni = 0; ni < 4; ++ni)
          ldsP[w][fg * 4 + r][ni * 16 + fr] = f32_bf16(s[ni][r]);
      }
    }
    asm volatile("s_waitcnt lgkmcnt(0)" ::: "memory");
    __builtin_amdgcn_sched_barrier(0);
    b16v8 pa0 = *(const b16v8*)&ldsP[w][fr][fg * 8];
    b16v8 pa1 = *(const b16v8*)&ldsP[w][fr][32 + fg * 8];
#pragma unroll
    for (int ni = 0; ni < 4; ++ni) {
      b16v8 vb0 = *(const b16v8*)&ldsVT[ni * 16 + fr][fg * 8];
      b16v8 vb1 = *(const b16v8*)&ldsVT[ni * 16 + fr][32 + fg * 8];
      oacc[ni] = MFMA(pa0, vb0, oacc[ni]);
      oacc[ni] = MFMA(pa1, vb1, oacc[ni]);
    }

    if (more) {
      __syncthreads();
      *(uint4*)&ldsK[sr][scb]  = kreg;
      *(uint4*)&ldsVT[sr][scb] = vreg;
      __syncthreads();
    }
  }

  const int bb = bh >> 4, hh = bh & 15;
#pragma unroll
  for (int r = 0; r < 4; ++r) {
    float rl = __builtin_amdgcn_rcpf(lsum[r]);
#pragma unroll
    for (int ni = 0; ni < 4; ++ni) {
      int t = qbase + w * 16 + fg * 4 + r;
      int d = ni * 16 + fr;
      y[((size_t)(bb * Tc + t)) * Cc + hh * Dc + d] = f32_bf16(oacc[ni][r] * rl);
    }
  }
}

// ---------------------------------------------------------------------------
// Deterministic combine (bf16 pairout): out[n] += p0*pair[s0] + p1*pair[s1]
// ---------------------------------------------------------------------------
__global__ __launch_bounds__(256) void combine_kernel(
    const unsigned short* __restrict__ pair, const float* __restrict__ tkp,
    const int* __restrict__ tok2slot, float* __restrict__ out) {
  const int n = blockIdx.x;
  const int c4 = threadIdx.x * 4;
  const int s0 = tok2slot[n * 2], s1 = tok2slot[n * 2 + 1];
  const float p0 = tkp[n * 2], p1 = tkp[n * 2 + 1];
  ushort4 a = *(const ushort4*)&pair[(size_t)s0 * Cc + c4];
  ushort4 b = *(const ushort4*)&pair[(size_t)s1 * Cc + c4];
  float4 o = *(float4*)&out[(size_t)n * Cc + c4];
  o.x += p0 * bf16_f32(a.x) + p1 * bf16_f32(b.x);
  o.y += p0 * bf16_f32(a.y) + p1 * bf16_f32(b.y);
  o.z += p0 * bf16_f32(a.z) + p1 * bf16_f32(b.z);
  o.w += p0 * bf16_f32(a.w) + p1 * bf16_f32(b.w);
  *(float4*)&out[(size_t)n * Cc + c4] = o;
}

// ---------------------------------------------------------------------------
extern "C" void kernel_launch(void* const* d_in, const int* in_sizes, int n_in,
                              void* d_out, int out_size, void* d_ws, size_t ws_size,
                              hipStream_t stream) {
  const float* x        = (const float*)d_in[0];
  const float* ln1_g    = (const float*)d_in[1];
  const float* ln1_b    = (const float*)d_in[2];
  const float* ln2_g    = (const float*)d_in[3];
  const float* ln2_b    = (const float*)d_in[4];
  const float* attn_w   = (const float*)d_in[5];
  const float* attn_b   = (const float*)d_in[6];
  const float* proj_w   = (const float*)d_in[7];
  const float* proj_b   = (const float*)d_in[8];
  const float* router_w = (const float*)d_in[9];
  const float* fc_w     = (const float*)d_in[10];
  const float* fc_b     = (const float*)d_in[11];
  const float* pj_w     = (const float*)d_in[12];
  const float* pj_b     = (const float*)d_in[13];
  float* out = (float*)d_out;

  char* ws = (char*)d_ws;
  size_t off = 0;
  auto alloc = [&](size_t bytes) -> void* {
    void* p = ws + off;
    off = (off + bytes + 255) & ~(size_t)255;
    return p;
  };
  unsigned short* attn_wT = (unsigned short*)alloc((size_t)3 * Cc * Cc * 2);
  unsigned short* proj_wT = (unsigned short*)alloc((size_t)Cc * Cc * 2);
  unsigned short* fc_wT   = (unsigned short*)alloc((size_t)Ec * HIDc * Cc * 2);
  unsigned short* pj_wT   = (unsigned short*)alloc((size_t)Ec * Cc * HIDc * 2);
  unsigned short* h    = (unsigned short*)alloc((size_t)Nc * Cc * 2);
  unsigned short* qb   = (unsigned short*)alloc((size_t)Nc * Cc * 2);   // [B,H,T,D]
  unsigned short* kbuf = (unsigned short*)alloc((size_t)Nc * Cc * 2);   // [B,H,T,D]
  unsigned short* vbuf = (unsigned short*)alloc((size_t)Nc * Cc * 2);   // [B,H,D,T]
  unsigned short* ybuf = (unsigned short*)alloc((size_t)Nc * Cc * 2);   // [N,C]
  unsigned short* he   = (unsigned short*)alloc((size_t)NPAIR * HIDc * 2);
  unsigned short* pairout = (unsigned short*)alloc((size_t)NPAIR * Cc * 2);
  int*   tki     = (int*)alloc((size_t)Nc * 2 * 4);
  float* tkp     = (float*)alloc((size_t)Nc * 2 * 4);
  int*   eoff    = (int*)alloc((Ec + 1) * 4);
  int*   slot_tok= (int*)alloc((size_t)NPAIR * 4);
  int*   tok2slot= (int*)alloc((size_t)Nc * 2 * 4);
  int*   tbl_e   = (int*)alloc(NRBMAX * 4);
  int*   tbl_r0  = (int*)alloc(NRBMAX * 4);
  int*   tbl_n   = (int*)alloc(4);
  (void)ws_size; (void)in_sizes; (void)n_in; (void)out_size;

  // 0) prologue: 4 weight transposes + ln1, ONE launch
  {
    ProJobs pj;
    pj.src[0] = attn_w;  pj.dst[0] = attn_wT; pj.K[0] = Cc;   pj.N[0] = 3 * Cc;
    pj.src[1] = proj_w;  pj.dst[1] = proj_wT; pj.K[1] = Cc;   pj.N[1] = Cc;
    pj.src[2] = fc_w;    pj.dst[2] = fc_wT;   pj.K[2] = Cc;   pj.N[2] = HIDc;
    pj.src[3] = pj_w;    pj.dst[3] = pj_wT;   pj.K[3] = HIDc; pj.N[3] = Cc;
    const int t0 = (3 * Cc / 64) * (Cc / 64);          // 768
    const int t1 = (Cc / 64) * (Cc / 64);              // 256
    const int t2 = (HIDc / 64) * (Cc / 64) * Ec;       // 8192
    const int t3 = (Cc / 64) * (HIDc / 64) * Ec;       // 8192
    pj.start[0] = 0;
    pj.start[1] = t0;
    pj.start[2] = t0 + t1;
    pj.start[3] = t0 + t1 + t2;
    pj.lnStart  = t0 + t1 + t2 + t3;                   // 17408
    pj.x = x; pj.ln_g = ln1_g; pj.ln_b = ln1_b; pj.h = h;
    prologue_all<<<pj.lnStart + Nc, 256, 0, stream>>>(pj);
  }

  // 1) QKV GEMM -> q/k [B,H,T,D], v^T [B,H,D,T]
  {
    GArgs a = {};
    a.A = h; a.Bt = attn_wT; a.bias = attn_b;
    a.M = Nc; a.N = 3 * Cc; a.K = Cc; a.lda = Cc; a.ldb = Cc; a.klen = Cc;
    a.outB = qb; a.outK = kbuf; a.outV = vbuf;
    gemm128b<0><<<dim3(3 * Cc / 128, Nc / 128, 1), 256, 0, stream>>>(a);
  }

  // 2) causal attention -> y [N,C] bf16 (heavy-first)
  attn_kernel<<<dim3(Tc / 128, Bc * Hc), 512, 0, stream>>>(qb, kbuf, vbuf, ybuf);

  // 3) proj + residual -> d_out (f32)
  {
    GArgs p = {};
    p.A = ybuf; p.Bt = proj_wT; p.bias = proj_b;
    p.M = Nc; p.N = Cc; p.K = Cc; p.lda = Cc; p.ldb = Cc; p.klen = Cc;
    p.outF = out; p.resid = x;
    gemm128b<1><<<dim3(Cc / 128, Nc / 128, 1), 256, 0, stream>>>(p);
  }

  // 4) LN2 + router -> h (bf16), top-2
  ln2_router_kernel<<<Nc, 256, 0, stream>>>(out, ln2_g, ln2_b, router_w, h, tki, tkp);

  // 5) routing: ONE single-block kernel
  route_kernel<<<1, 256, 0, stream>>>(tki, eoff, slot_tok, tok2slot,
                                      tbl_e, tbl_r0, tbl_n);

  // 6) fc -> he [NPAIR][HID] bf16 w/ GELU (exact rowblock grid)
  {
    GArgs f = {};
    f.A = h; f.Bt = fc_wT; f.bias = fc_b;
    f.M = Nc; f.N = HIDc; f.K = Cc; f.lda = Cc; f.ldb = Cc; f.klen = Cc;
    f.Bstride = (size_t)HIDc * Cc; f.biasStride = HIDc;
    f.eoff = eoff; f.slot_tok = slot_tok;
    f.tbl_e = tbl_e; f.tbl_r0 = tbl_r0; f.tbl_n = tbl_n;
    f.outB = he;
    gemm128b<2><<<dim3(HIDc / 128, NRBMAX, 1), 256, 0, stream>>>(f);
  }

  // 7) pj (single K pass) -> pairout [NPAIR][C] bf16 (bias incl.)
  {
    GArgs pjj = {};
    pjj.A = he; pjj.Bt = pj_wT; pjj.bias = pj_b;
    pjj.M = Nc; pjj.N = Cc; pjj.K = HIDc; pjj.lda = HIDc; pjj.ldb = HIDc; pjj.klen = HIDc;
    pjj.Bstride = (size_t)Cc * HIDc; pjj.biasStride = Cc;
    pjj.eoff = eoff;
    pjj.tbl_e = tbl_e; pjj.tbl_r0 = tbl_r0; pjj.tbl_n = tbl_n;
    pjj.outB = pairout;
    gemm128b<3><<<dim3(Cc / 128, NRBMAX, 1), 256, 0, stream>>>(pjj);
  }

  // 8) deterministic combine into d_out
  combine_kernel<<<Nc, 256, 0, stream>>>(pairout, tkp, tok2slot, out);
}

// Round 18
// 546.515 us; speedup vs baseline: 1.1816x; 1.0006x over previous
//
#include <hip/hip_runtime.h>
#include <math.h>

// ---------------------------------------------------------------------------
// Fused transformer block w/ MoE (B=2,T=2048,C=1024,H=16,D=64,E=8,topK=2)
// Round 18: r17 (546.8us) + T5 s_setprio(1) around attn MFMA clusters
// (catalog m191: +4-7% on attn's independent-block regime; GEMMs untouched
// per m190 null). Everything else bit-identical to r17.
// ---------------------------------------------------------------------------

typedef __bf16 b16v8 __attribute__((ext_vector_type(8)));
typedef float f32x4 __attribute__((ext_vector_type(4)));

#define MFMA(a, b, c) __builtin_amdgcn_mfma_f32_16x16x32_bf16(a, b, c, 0, 0, 0)

#define GLOAD_LDS16(g, l)                                          \
  __builtin_amdgcn_global_load_lds(                                \
      (const __attribute__((address_space(1))) void*)(g),          \
      (__attribute__((address_space(3))) void*)(l), 16, 0, 0)

constexpr int Bc = 2, Tc = 2048, Cc = 1024, Hc = 16, Dc = 64;
constexpr int Nc = Bc * Tc;       // 4096 tokens
constexpr int HIDc = 4096;        // 4*C
constexpr int Ec = 8;
constexpr int NPAIR = Nc * 2;     // 8192
constexpr int NRBMAX = NPAIR / 128 + Ec;  // 72
constexpr float LOG2E = 1.4426950408889634f;

__device__ inline unsigned short f32_bf16(float f) {
  union { float f; unsigned u; } x; x.f = f;
  unsigned r = x.u + 0x7fffu + ((x.u >> 16) & 1u);   // RNE
  return (unsigned short)(r >> 16);
}

__device__ inline float bf16_f32(unsigned short u) {
  union { unsigned u; float f; } x; x.u = ((unsigned)u) << 16;
  return x.f;
}

// gelu(x) = x * sigmoid(1.595769122*(x+0.044715x^3)); exp2-domain
__device__ inline float gelu_f(float x) {
  float t = 2.3021188f * x * (1.f + 0.044715f * x * x);
  float e = __builtin_amdgcn_exp2f(-t);
  return x * __builtin_amdgcn_rcpf(1.f + e);
}

// LDS element index for [row][64-elem] rows with 16B-granule XOR swizzle.
__device__ inline int swz(int row, int g) {
  return row * 64 + ((g ^ (row & 7)) * 8);
}

// ---------------------------------------------------------------------------
// Fused prologue: 4 weight transpose+convert jobs AND ln1 in ONE launch.
// ---------------------------------------------------------------------------
struct ProJobs {
  const float* src[4];
  unsigned short* dst[4];
  int K[4], N[4];
  int start[4];
  int lnStart;                 // first ln1 block
  const float* x;
  const float* ln_g;
  const float* ln_b;
  unsigned short* h;
};

__global__ __launch_bounds__(256) void prologue_all(ProJobs j) {
  const int id = blockIdx.x;
  const int tid = threadIdx.x;

  if (id >= j.lnStart) {
    // ---- ln1 body ----
    const int row = id - j.lnStart;
    const float* xr = j.x + (size_t)row * Cc;
    float v[4]; float s = 0.f, q = 0.f;
#pragma unroll
    for (int jj = 0; jj < 4; ++jj) {
      v[jj] = xr[tid + jj * 256]; s += v[jj]; q += v[jj] * v[jj];
    }
#pragma unroll
    for (int m = 1; m <= 32; m <<= 1) { s += __shfl_xor(s, m); q += __shfl_xor(q, m); }
    __shared__ float red[2][4];
    const int w = tid >> 6;
    if ((tid & 63) == 0) { red[0][w] = s; red[1][w] = q; }
    __syncthreads();
    s = red[0][0] + red[0][1] + red[0][2] + red[0][3];
    q = red[1][0] + red[1][1] + red[1][2] + red[1][3];
    const float mean = s * (1.f / Cc);
    const float var = q * (1.f / Cc) - mean * mean;
    const float rstd = rsqrtf(var + 1e-5f);
#pragma unroll
    for (int jj = 0; jj < 4; ++jj) {
      int c = tid + jj * 256;
      j.h[(size_t)row * Cc + c] = f32_bf16((v[jj] - mean) * rstd * j.ln_g[c] + j.ln_b[c]);
    }
    return;
  }

  // ---- convT body ----
  int which = 0;
#pragma unroll
  for (int q = 1; q < 4; ++q) which = (id >= j.start[q]) ? q : which;
  const int local = id - j.start[which];
  const int K = j.K[which], N = j.N[which];
  const int ntx = N >> 6, nty = K >> 6;
  const int perb = ntx * nty;
  const int batch = local / perb;
  const int rem = local - batch * perb;
  const int n0 = (rem % ntx) * 64, k0 = (rem / ntx) * 64;
  const float* src = j.src[which] + (size_t)batch * K * N;
  unsigned short* dst = j.dst[which] + (size_t)batch * K * N;

  __shared__ float t[64][65];
#pragma unroll
  for (int jj = 0; jj < 4; ++jj) {
    int idx = jj * 256 + tid;
    int r = idx >> 4;
    int c4 = (idx & 15) << 2;
    float4 v = *(const float4*)&src[(size_t)(k0 + r) * N + n0 + c4];
    t[r][c4] = v.x; t[r][c4 + 1] = v.y; t[r][c4 + 2] = v.z; t[r][c4 + 3] = v.w;
  }
  __syncthreads();
#pragma unroll
  for (int jj = 0; jj < 4; ++jj) {
    int idx = jj * 256 + tid;
    int n = idx >> 4;
    int k4 = (idx & 15) << 2;
    ushort4 o;
    o.x = f32_bf16(t[k4][n]);
    o.y = f32_bf16(t[k4 + 1][n]);
    o.z = f32_bf16(t[k4 + 2][n]);
    o.w = f32_bf16(t[k4 + 3][n]);
    *(ushort4*)&dst[(size_t)(n0 + n) * K + k0 + k4] = o;
  }
}

// ---------------------------------------------------------------------------
// LN2 + router (f32 router math).
// ---------------------------------------------------------------------------
__global__ __launch_bounds__(256) void ln2_router_kernel(
    const float* __restrict__ x, const float* __restrict__ g,
    const float* __restrict__ b, const float* __restrict__ rw,
    unsigned short* __restrict__ out, int* __restrict__ tki, float* __restrict__ tkp) {
  const int row = blockIdx.x;
  const int tid = threadIdx.x;
  const float* xr = x + (size_t)row * Cc;
  float v[4]; float s = 0.f, q = 0.f;
#pragma unroll
  for (int j = 0; j < 4; ++j) { v[j] = xr[tid + j * 256]; s += v[j]; q += v[j] * v[j]; }
#pragma unroll
  for (int m = 1; m <= 32; m <<= 1) { s += __shfl_xor(s, m); q += __shfl_xor(q, m); }
  __shared__ float red[2][4];
  const int w = tid >> 6;
  if ((tid & 63) == 0) { red[0][w] = s; red[1][w] = q; }
  __syncthreads();
  s = red[0][0] + red[0][1] + red[0][2] + red[0][3];
  q = red[1][0] + red[1][1] + red[1][2] + red[1][3];
  const float mean = s * (1.f / Cc);
  const float var = q * (1.f / Cc) - mean * mean;
  const float rstd = rsqrtf(var + 1e-5f);
  float lg[8] = {0.f, 0.f, 0.f, 0.f, 0.f, 0.f, 0.f, 0.f};
#pragma unroll
  for (int j = 0; j < 4; ++j) {
    int c = tid + j * 256;
    float nv = (v[j] - mean) * rstd * g[c] + b[c];
    out[(size_t)row * Cc + c] = f32_bf16(nv);
    const float* rwc = rw + c * 8;
#pragma unroll
    for (int e = 0; e < 8; ++e) lg[e] += nv * rwc[e];
  }
#pragma unroll
  for (int m = 1; m <= 32; m <<= 1) {
#pragma unroll
    for (int e = 0; e < 8; ++e) lg[e] += __shfl_xor(lg[e], m);
  }
  __shared__ float rl[4][8];
  if ((tid & 63) == 0) {
#pragma unroll
    for (int e = 0; e < 8; ++e) rl[w][e] = lg[e];
  }
  __syncthreads();
  if (tid == 0) {
    float L[8];
#pragma unroll
    for (int e = 0; e < 8; ++e) L[e] = rl[0][e] + rl[1][e] + rl[2][e] + rl[3][e];
    int i1 = 0;
    for (int e = 1; e < 8; ++e) if (L[e] > L[i1]) i1 = e;
    int i2 = (i1 == 0) ? 1 : 0;
    for (int e = 0; e < 8; ++e) if (e != i1 && L[e] > L[i2]) i2 = e;
    float e2 = expf(L[i2] - L[i1]);
    float inv = 1.f / (1.f + e2);
    tki[row * 2] = i1; tki[row * 2 + 1] = i2;
    tkp[row * 2] = inv; tkp[row * 2 + 1] = e2 * inv;
  }
}

// ---------------------------------------------------------------------------
// Fused routing: histogram + offsets + rowblock table + slot assignment.
// ---------------------------------------------------------------------------
__global__ __launch_bounds__(256) void route_kernel(
    const int* __restrict__ tki,
    int* __restrict__ eoff, int* __restrict__ slot_tok,
    int* __restrict__ tok2slot, int* __restrict__ tbl_e,
    int* __restrict__ tbl_r0, int* __restrict__ tbl_n) {
  __shared__ int cnt[8];
  const int tid = threadIdx.x;
  if (tid < 8) cnt[tid] = 0;
  __syncthreads();
  for (int n = tid; n < Nc; n += 256) {
    atomicAdd(&cnt[tki[n * 2]], 1);
    atomicAdd(&cnt[tki[n * 2 + 1]], 1);
  }
  __syncthreads();
  if (tid == 0) {
    int s = 0, nb = 0;
    int base[8];
    for (int e = 0; e < Ec; ++e) {
      base[e] = s; eoff[e] = s;
      for (int r = 0; r < cnt[e]; r += 128) {
        tbl_e[nb] = e; tbl_r0[nb] = r; ++nb;
      }
      s += cnt[e];
    }
    eoff[Ec] = s;
    *tbl_n = nb;
    for (int e = 0; e < Ec; ++e) cnt[e] = base[e];   // reuse as cursors
  }
  __syncthreads();
  for (int n = tid; n < Nc; n += 256) {
#pragma unroll
    for (int kk = 0; kk < 2; ++kk) {
      int e = tki[n * 2 + kk];
      int slot = atomicAdd(&cnt[e], 1);
      slot_tok[slot] = n;
      tok2slot[n * 2 + kk] = slot;
    }
  }
}

// ---------------------------------------------------------------------------
struct GArgs {
  const unsigned short* A;    // bf16 [M][lda]
  const unsigned short* Bt;   // bf16 [N][ldb] (+ e*Bstride)
  const float* bias;          // f32 [N]      (+ e*biasStride)
  int M, N, K, lda, ldb, klen;
  size_t Bstride; int biasStride;
  const int* eoff;            // [E+1] (MODE 2/3)
  const int* slot_tok;        // (MODE 2)
  const int* tbl_e;           // rowblock table (MODE 2/3)
  const int* tbl_r0;
  const int* tbl_n;
  float* outF;                // MODE 1: out
  const float* resid;         // MODE 1
  unsigned short* outB;       // MODE 2: he ; MODE 3: pairout(bf16); MODE 0: q
  unsigned short* outK;       // MODE 0: k
  unsigned short* outV;       // MODE 0: v^T [B,H,D,T]
};

// ---------------------------------------------------------------------------
// 128x128 tile, BK=64, 4 waves (2x2), SINGLE buffer, XOR granule swizzle.
// 32 KiB LDS -> ~5 blocks/CU (r8 structure, session best).
// MODE: 0=QKV scatter, 1=proj+resid, 2=fc gather+gelu, 3=pj -> pairout(bf16)
// ---------------------------------------------------------------------------
template <int MODE>
__global__ __launch_bounds__(256) void gemm128b(GArgs g) {
  int e = 0, s0 = 0, Meff = g.M, row0;
  if constexpr (MODE == 2 || MODE == 3) {
    if ((int)blockIdx.y >= *g.tbl_n) return;
    e = g.tbl_e[blockIdx.y];
    row0 = g.tbl_r0[blockIdx.y];
    s0 = g.eoff[e];
    Meff = g.eoff[e + 1] - s0;
  } else {
    row0 = blockIdx.y * 128;
  }
  const int col0 = blockIdx.x * 128;

  __shared__ __align__(16) unsigned short As[128 * 64];
  __shared__ __align__(16) unsigned short Bs[128 * 64];

  const int tid = threadIdx.x;
  const int lane = tid & 63, w = tid >> 6;
  const int wr = w >> 1, wc = w & 1;
  const int fr = lane & 15, fg = lane >> 4;

  const unsigned short* Bt = g.Bt + (size_t)e * g.Bstride;
  const float* bias = g.bias + (size_t)e * g.biasStride;

  // LDS dest linear (gload_lds); GLOBAL source granule pre-swizzled (#21).
  size_t aaddr[4], baddr[4];
#pragma unroll
  for (int i = 0; i < 4; ++i) {
    int pos = i * 256 + tid;
    int r = pos >> 3;
    int c8 = ((pos & 7) ^ (r & 7)) * 8;
    int gr = row0 + r;
    if (gr >= Meff) gr = Meff - 1;
    int srcrow;
    if constexpr (MODE == 2) srcrow = g.slot_tok[s0 + gr];
    else if constexpr (MODE == 3) srcrow = s0 + gr;
    else srcrow = gr;
    aaddr[i] = (size_t)srcrow * g.lda + c8;
    baddr[i] = (size_t)(col0 + r) * g.ldb + c8;
  }

  auto STAGE = [&](int k0) {
#pragma unroll
    for (int i = 0; i < 4; ++i) {
      GLOAD_LDS16(g.A + aaddr[i] + k0, &As[i * 2048 + w * 512]);
      GLOAD_LDS16(Bt + baddr[i] + k0, &Bs[i * 2048 + w * 512]);
    }
  };

  f32x4 acc[4][4] = {};
  const int nt = g.klen / 64;

  for (int t = 0; t < nt; ++t) {
    if (t) __syncthreads();
    STAGE(t * 64);
    __syncthreads();
    b16v8 af[4][2], bf_[4][2];
#pragma unroll
    for (int mi = 0; mi < 4; ++mi) {
      const int ar = wr * 64 + mi * 16 + fr;
      af[mi][0] = *(const b16v8*)&As[swz(ar, fg)];
      af[mi][1] = *(const b16v8*)&As[swz(ar, 4 + fg)];
    }
#pragma unroll
    for (int ni = 0; ni < 4; ++ni) {
      const int br = wc * 64 + ni * 16 + fr;
      bf_[ni][0] = *(const b16v8*)&Bs[swz(br, fg)];
      bf_[ni][1] = *(const b16v8*)&Bs[swz(br, 4 + fg)];
    }
#pragma unroll
    for (int mi = 0; mi < 4; ++mi)
#pragma unroll
      for (int ni = 0; ni < 4; ++ni) {
        acc[mi][ni] = MFMA(af[mi][0], bf_[ni][0], acc[mi][ni]);
        acc[mi][ni] = MFMA(af[mi][1], bf_[ni][1], acc[mi][ni]);
      }
  }

#pragma unroll
  for (int mi = 0; mi < 4; ++mi) {
#pragma unroll
    for (int ni = 0; ni < 4; ++ni) {
#pragma unroll
      for (int rr = 0; rr < 4; ++rr) {
        int row = row0 + wr * 64 + mi * 16 + fg * 4 + rr;
        int col = col0 + wc * 64 + ni * 16 + fr;
        if (row >= Meff) continue;
        float val = acc[mi][ni][rr] + bias[col];
        if constexpr (MODE == 0) {
          int bb = row >> 11, tt = row & (Tc - 1);
          int which = col >> 10, cj = col & (Cc - 1);
          int hd = cj >> 6, d = cj & 63;
          if (which == 0)
            g.outB[(((size_t)(bb * Hc + hd)) * Tc + tt) * Dc + d] = f32_bf16(val);
          else if (which == 1)
            g.outK[(((size_t)(bb * Hc + hd)) * Tc + tt) * Dc + d] = f32_bf16(val);
          else
            g.outV[(((size_t)(bb * Hc + hd)) * Dc + d) * Tc + tt] = f32_bf16(val);
        } else if constexpr (MODE == 1) {
          size_t o = (size_t)row * g.N + col;
          g.outF[o] = val + g.resid[o];
        } else if constexpr (MODE == 2) {
          g.outB[(size_t)(s0 + row) * g.N + col] = f32_bf16(gelu_f(val));
        } else {
          g.outB[(size_t)(s0 + row) * g.N + col] = f32_bf16(val);
        }
      }
    }
  }
}

// ---------------------------------------------------------------------------
// Flash-style causal attention. 8 waves, 128 q-rows, KV tile 64.
// Heavy-first dispatch; T14 reg-prefetch; exact no-growth fast path;
// T5 s_setprio(1) around MFMA clusters (m191 regime: independent blocks).
// ---------------------------------------------------------------------------
__global__ __launch_bounds__(512) void attn_kernel(
    const unsigned short* __restrict__ q, const unsigned short* __restrict__ k,
    const unsigned short* __restrict__ v, unsigned short* __restrict__ y) {
  const int qt = gridDim.x - 1 - blockIdx.x;   // heavy-first
  const int bh = blockIdx.y;
  const int qbase = qt * 128;
  __shared__ __align__(16) unsigned short ldsK[64][72];
  __shared__ __align__(16) unsigned short ldsVT[64][72];     // [d][kv]
  __shared__ __align__(16) unsigned short ldsP[8][16][72];
  const int tid = threadIdx.x, lane = tid & 63, w = tid >> 6;
  const int fr = lane & 15, fg = lane >> 4;
  const size_t base = (size_t)bh * Tc * Dc;
  const int qrow = qbase + w * 16 + fr;
  b16v8 qa0 = *(const b16v8*)(q + base + (size_t)qrow * Dc + fg * 8);
  b16v8 qa1 = *(const b16v8*)(q + base + (size_t)qrow * Dc + 32 + fg * 8);
  float m[4], lsum[4] = {0.f, 0.f, 0.f, 0.f};
#pragma unroll
  for (int r = 0; r < 4; ++r) m[r] = -3.0e38f;
  f32x4 oacc[4] = {};
  constexpr float SC = 0.125f * LOG2E;

  const int sr = tid >> 3, scb = (tid & 7) * 8;
  const int ntile = (qbase + 128) / 64;

  *(uint4*)&ldsK[sr][scb]  = *(const uint4*)(k + base + (size_t)sr * Dc + scb);
  *(uint4*)&ldsVT[sr][scb] = *(const uint4*)(v + base + (size_t)sr * Tc + scb);
  __syncthreads();

  for (int ti = 0; ti < ntile; ++ti) {
    const int kb = ti * 64;
    uint4 kreg, vreg;
    const bool more = (ti + 1 < ntile);
    if (more) {
      const int kn = kb + 64;
      kreg = *(const uint4*)(k + base + (size_t)(kn + sr) * Dc + scb);
      vreg = *(const uint4*)(v + base + (size_t)sr * Tc + kn + scb);
    }

    f32x4 s[4];
    __builtin_amdgcn_s_setprio(1);
#pragma unroll
    for (int ni = 0; ni < 4; ++ni) {
      b16v8 kb0 = *(const b16v8*)&ldsK[ni * 16 + fr][fg * 8];
      b16v8 kb1 = *(const b16v8*)&ldsK[ni * 16 + fr][32 + fg * 8];
      f32x4 z = {};
      z = MFMA(qa0, kb0, z);
      z = MFMA(qa1, kb1, z);
      s[ni] = z;
    }
    __builtin_amdgcn_s_setprio(0);
    const bool diag = (kb + 64 > qbase + w * 16);
#pragma unroll
    for (int ni = 0; ni < 4; ++ni) {
#pragma unroll
      for (int r = 0; r < 4; ++r) {
        float sv = s[ni][r] * SC;
        if (diag) {
          int gq = qbase + w * 16 + fg * 4 + r;
          int kv = kb + ni * 16 + fr;
          if (kv > gq) sv = -3.0e38f;
        }
        s[ni][r] = sv;
      }
    }
    float mx[4];
    bool grow = false;
#pragma unroll
    for (int r = 0; r < 4; ++r) {
      float t = fmaxf(fmaxf(s[0][r], s[1][r]), fmaxf(s[2][r], s[3][r]));
#pragma unroll
      for (int msk = 1; msk <= 8; msk <<= 1) t = fmaxf(t, __shfl_xor(t, msk));
      mx[r] = t;
      grow = grow || (t > m[r]);
    }
    if (__any(grow)) {
#pragma unroll
      for (int r = 0; r < 4; ++r) {
        float mnew = fmaxf(m[r], mx[r]);
        float alpha = __builtin_amdgcn_exp2f(m[r] - mnew);
        float psum = 0.f;
#pragma unroll
        for (int ni = 0; ni < 4; ++ni) {
          float pp = __builtin_amdgcn_exp2f(s[ni][r] - mnew);
          s[ni][r] = pp;
          psum += pp;
        }
#pragma unroll
        for (int msk = 1; msk <= 8; msk <<= 1) psum += __shfl_xor(psum, msk);
        lsum[r] = lsum[r] * alpha + psum;
        m[r] = mnew;
#pragma unroll
        for (int ni = 0; ni < 4; ++ni) {
          oacc[ni][r] = oacc[ni][r] * alpha;
          ldsP[w][fg * 4 + r][ni * 16 + fr] = f32_bf16(s[ni][r]);
        }
      }
    } else {
#pragma unroll
      for (int r = 0; r < 4; ++r) {
        float psum = 0.f;
#pragma unroll
        for (int ni = 0; ni < 4; ++ni) {
          float pp = __builtin_amdgcn_exp2f(s[ni][r] - m[r]);
          s[ni][r] = pp;
          psum += pp;
        }
#pragma unroll
        for (int msk = 1; msk <= 8; msk <<= 1) psum += __shfl_xor(psum, msk);
        lsum[r] += psum;
#pragma unroll
        for (int ni = 0; ni < 4; ++ni)
          ldsP[w][fg * 4 + r][ni * 16 + fr] = f32_bf16(s[ni][r]);
      }
    }
    asm volatile("s_waitcnt lgkmcnt(0)" ::: "memory");
    __builtin_amdgcn_sched_barrier(0);
    b16v8 pa0 = *(const b16v8*)&ldsP[w][fr][fg * 8];
    b16v8 pa1 = *(const b16v8*)&ldsP[w][fr][32 + fg * 8];
    __builtin_amdgcn_s_setprio(1);
#pragma unroll
    for (int ni = 0; ni < 4; ++ni) {
      b16v8 vb0 = *(const b16v8*)&ldsVT[ni * 16 + fr][fg * 8];
      b16v8 vb1 = *(const b16v8*)&ldsVT[ni * 16 + fr][32 + fg * 8];
      oacc[ni] = MFMA(pa0, vb0, oacc[ni]);
      oacc[ni] = MFMA(pa1, vb1, oacc[ni]);
    }
    __builtin_amdgcn_s_setprio(0);

    if (more) {
      __syncthreads();
      *(uint4*)&ldsK[sr][scb]  = kreg;
      *(uint4*)&ldsVT[sr][scb] = vreg;
      __syncthreads();
    }
  }

  const int bb = bh >> 4, hh = bh & 15;
#pragma unroll
  for (int r = 0; r < 4; ++r) {
    float rl = __builtin_amdgcn_rcpf(lsum[r]);
#pragma unroll
    for (int ni = 0; ni < 4; ++ni) {
      int t = qbase + w * 16 + fg * 4 + r;
      int d = ni * 16 + fr;
      y[((size_t)(bb * Tc + t)) * Cc + hh * Dc + d] = f32_bf16(oacc[ni][r] * rl);
    }
  }
}

// ---------------------------------------------------------------------------
// Deterministic combine (bf16 pairout): out[n] += p0*pair[s0] + p1*pair[s1]
// ---------------------------------------------------------------------------
__global__ __launch_bounds__(256) void combine_kernel(
    const unsigned short* __restrict__ pair, const float* __restrict__ tkp,
    const int* __restrict__ tok2slot, float* __restrict__ out) {
  const int n = blockIdx.x;
  const int c4 = threadIdx.x * 4;
  const int s0 = tok2slot[n * 2], s1 = tok2slot[n * 2 + 1];
  const float p0 = tkp[n * 2], p1 = tkp[n * 2 + 1];
  ushort4 a = *(const ushort4*)&pair[(size_t)s0 * Cc + c4];
  ushort4 b = *(const ushort4*)&pair[(size_t)s1 * Cc + c4];
  float4 o = *(float4*)&out[(size_t)n * Cc + c4];
  o.x += p0 * bf16_f32(a.x) + p1 * bf16_f32(b.x);
  o.y += p0 * bf16_f32(a.y) + p1 * bf16_f32(b.y);
  o.z += p0 * bf16_f32(a.z) + p1 * bf16_f32(b.z);
  o.w += p0 * bf16_f32(a.w) + p1 * bf16_f32(b.w);
  *(float4*)&out[(size_t)n * Cc + c4] = o;
}

// ---------------------------------------------------------------------------
extern "C" void kernel_launch(void* const* d_in, const int* in_sizes, int n_in,
                              void* d_out, int out_size, void* d_ws, size_t ws_size,
                              hipStream_t stream) {
  const float* x        = (const float*)d_in[0];
  const float* ln1_g    = (const float*)d_in[1];
  const float* ln1_b    = (const float*)d_in[2];
  const float* ln2_g    = (const float*)d_in[3];
  const float* ln2_b    = (const float*)d_in[4];
  const float* attn_w   = (const float*)d_in[5];
  const float* attn_b   = (const float*)d_in[6];
  const float* proj_w   = (const float*)d_in[7];
  const float* proj_b   = (const float*)d_in[8];
  const float* router_w = (const float*)d_in[9];
  const float* fc_w     = (const float*)d_in[10];
  const float* fc_b     = (const float*)d_in[11];
  const float* pj_w     = (const float*)d_in[12];
  const float* pj_b     = (const float*)d_in[13];
  float* out = (float*)d_out;

  char* ws = (char*)d_ws;
  size_t off = 0;
  auto alloc = [&](size_t bytes) -> void* {
    void* p = ws + off;
    off = (off + bytes + 255) & ~(size_t)255;
    return p;
  };
  unsigned short* attn_wT = (unsigned short*)alloc((size_t)3 * Cc * Cc * 2);
  unsigned short* proj_wT = (unsigned short*)alloc((size_t)Cc * Cc * 2);
  unsigned short* fc_wT   = (unsigned short*)alloc((size_t)Ec * HIDc * Cc * 2);
  unsigned short* pj_wT   = (unsigned short*)alloc((size_t)Ec * Cc * HIDc * 2);
  unsigned short* h    = (unsigned short*)alloc((size_t)Nc * Cc * 2);
  unsigned short* qb   = (unsigned short*)alloc((size_t)Nc * Cc * 2);   // [B,H,T,D]
  unsigned short* kbuf = (unsigned short*)alloc((size_t)Nc * Cc * 2);   // [B,H,T,D]
  unsigned short* vbuf = (unsigned short*)alloc((size_t)Nc * Cc * 2);   // [B,H,D,T]
  unsigned short* ybuf = (unsigned short*)alloc((size_t)Nc * Cc * 2);   // [N,C]
  unsigned short* he   = (unsigned short*)alloc((size_t)NPAIR * HIDc * 2);
  unsigned short* pairout = (unsigned short*)alloc((size_t)NPAIR * Cc * 2);
  int*   tki     = (int*)alloc((size_t)Nc * 2 * 4);
  float* tkp     = (float*)alloc((size_t)Nc * 2 * 4);
  int*   eoff    = (int*)alloc((Ec + 1) * 4);
  int*   slot_tok= (int*)alloc((size_t)NPAIR * 4);
  int*   tok2slot= (int*)alloc((size_t)Nc * 2 * 4);
  int*   tbl_e   = (int*)alloc(NRBMAX * 4);
  int*   tbl_r0  = (int*)alloc(NRBMAX * 4);
  int*   tbl_n   = (int*)alloc(4);
  (void)ws_size; (void)in_sizes; (void)n_in; (void)out_size;

  // 0) prologue: 4 weight transposes + ln1, ONE launch
  {
    ProJobs pj;
    pj.src[0] = attn_w;  pj.dst[0] = attn_wT; pj.K[0] = Cc;   pj.N[0] = 3 * Cc;
    pj.src[1] = proj_w;  pj.dst[1] = proj_wT; pj.K[1] = Cc;   pj.N[1] = Cc;
    pj.src[2] = fc_w;    pj.dst[2] = fc_wT;   pj.K[2] = Cc;   pj.N[2] = HIDc;
    pj.src[3] = pj_w;    pj.dst[3] = pj_wT;   pj.K[3] = HIDc; pj.N[3] = Cc;
    const int t0 = (3 * Cc / 64) * (Cc / 64);          // 768
    const int t1 = (Cc / 64) * (Cc / 64);              // 256
    const int t2 = (HIDc / 64) * (Cc / 64) * Ec;       // 8192
    const int t3 = (Cc / 64) * (HIDc / 64) * Ec;       // 8192
    pj.start[0] = 0;
    pj.start[1] = t0;
    pj.start[2] = t0 + t1;
    pj.start[3] = t0 + t1 + t2;
    pj.lnStart  = t0 + t1 + t2 + t3;                   // 17408
    pj.x = x; pj.ln_g = ln1_g; pj.ln_b = ln1_b; pj.h = h;
    prologue_all<<<pj.lnStart + Nc, 256, 0, stream>>>(pj);
  }

  // 1) QKV GEMM -> q/k [B,H,T,D], v^T [B,H,D,T]
  {
    GArgs a = {};
    a.A = h; a.Bt = attn_wT; a.bias = attn_b;
    a.M = Nc; a.N = 3 * Cc; a.K = Cc; a.lda = Cc; a.ldb = Cc; a.klen = Cc;
    a.outB = qb; a.outK = kbuf; a.outV = vbuf;
    gemm128b<0><<<dim3(3 * Cc / 128, Nc / 128, 1), 256, 0, stream>>>(a);
  }

  // 2) causal attention -> y [N,C] bf16 (heavy-first, setprio)
  attn_kernel<<<dim3(Tc / 128, Bc * Hc), 512, 0, stream>>>(qb, kbuf, vbuf, ybuf);

  // 3) proj + residual -> d_out (f32)
  {
    GArgs p = {};
    p.A = ybuf; p.Bt = proj_wT; p.bias = proj_b;
    p.M = Nc; p.N = Cc; p.K = Cc; p.lda = Cc; p.ldb = Cc; p.klen = Cc;
    p.outF = out; p.resid = x;
    gemm128b<1><<<dim3(Cc / 128, Nc / 128, 1), 256, 0, stream>>>(p);
  }

  // 4) LN2 + router -> h (bf16), top-2
  ln2_router_kernel<<<Nc, 256, 0, stream>>>(out, ln2_g, ln2_b, router_w, h, tki, tkp);

  // 5) routing: ONE single-block kernel
  route_kernel<<<1, 256, 0, stream>>>(tki, eoff, slot_tok, tok2slot,
                                      tbl_e, tbl_r0, tbl_n);

  // 6) fc -> he [NPAIR][HID] bf16 w/ GELU (exact rowblock grid)
  {
    GArgs f = {};
    f.A = h; f.Bt = fc_wT; f.bias = fc_b;
    f.M = Nc; f.N = HIDc; f.K = Cc; f.lda = Cc; f.ldb = Cc; f.klen = Cc;
    f.Bstride = (size_t)HIDc * Cc; f.biasStride = HIDc;
    f.eoff = eoff; f.slot_tok = slot_tok;
    f.tbl_e = tbl_e; f.tbl_r0 = tbl_r0; f.tbl_n = tbl_n;
    f.outB = he;
    gemm128b<2><<<dim3(HIDc / 128, NRBMAX, 1), 256, 0, stream>>>(f);
  }

  // 7) pj (single K pass) -> pairout [NPAIR][C] bf16 (bias incl.)
  {
    GArgs pjj = {};
    pjj.A = he; pjj.Bt = pj_wT; pjj.bias = pj_b;
    pjj.M = Nc; pjj.N = Cc; pjj.K = HIDc; pjj.lda = HIDc; pjj.ldb = HIDc; pjj.klen = HIDc;
    pjj.Bstride = (size_t)Cc * HIDc; pjj.biasStride = Cc;
    pjj.eoff = eoff;
    pjj.tbl_e = tbl_e; pjj.tbl_r0 = tbl_r0; pjj.tbl_n = tbl_n;
    pjj.outB = pairout;
    gemm128b<3><<<dim3(Cc / 128, NRBMAX, 1), 256, 0, stream>>>(pjj);
  }

  // 8) deterministic combine into d_out
  combine_kernel<<<Nc, 256, 0, stream>>>(pairout, tkp, tok2slot, out);
}